// Round 1
// baseline (1058.964 us; speedup 1.0000x reference)
//
#include <hip/hip_runtime.h>
#include <stdint.h>

// Problem constants (see reference)
constexpr int kHW    = 16384;   // 128*128 pixels (grid shared across batch)
constexpr int kB     = 4;
constexpr int kM     = 256;     // tokens
constexpr int kHD    = 256;     // hidden dim
constexpr int kDH    = 64;      // head dim
constexpr int kINNER = 128;     // heads*dh

// ---------------- helpers ----------------
__device__ __forceinline__ unsigned short f2bf(float f) {
  unsigned u = __float_as_uint(f);
  unsigned r = (u + 0x7fffu + ((u >> 16) & 1u)) >> 16;
  return (unsigned short)r;
}

__device__ __forceinline__ void unpack8(uint4 v, float* f) {
  f[0] = __uint_as_float(v.x << 16); f[1] = __uint_as_float(v.x & 0xffff0000u);
  f[2] = __uint_as_float(v.y << 16); f[3] = __uint_as_float(v.y & 0xffff0000u);
  f[4] = __uint_as_float(v.z << 16); f[5] = __uint_as_float(v.z & 0xffff0000u);
  f[6] = __uint_as_float(v.w << 16); f[7] = __uint_as_float(v.w & 0xffff0000u);
}

// ---------------- kernel 1: kv = tokens @ tokvW, write K (chunked) + V (transposed), bf16 ----------------
// K layout: kc[b][h][dblk(8)][j(256)][e(8)]   (d = dblk*8+e)  -> lane-j reads 16B contiguous
// V layout: vt[b][h][d(64)][j(256)]
__global__ __launch_bounds__(256) void kv_kernel(
    const float* __restrict__ tokens, const float* __restrict__ tokvW,
    unsigned short* __restrict__ kc_ws, unsigned short* __restrict__ vt_ws)
{
  __shared__ __align__(16) float tok[256];
  int b = blockIdx.y, j = blockIdx.x, c = threadIdx.x;
  tok[c] = tokens[(b * kM + j) * 256 + c];
  __syncthreads();
  float acc = 0.f;
  for (int i4 = 0; i4 < 64; i4++) {
    float4 t4 = *(const float4*)&tok[i4 * 4];
    acc += t4.x * tokvW[(i4*4+0)*256 + c] + t4.y * tokvW[(i4*4+1)*256 + c]
         + t4.z * tokvW[(i4*4+2)*256 + c] + t4.w * tokvW[(i4*4+3)*256 + c];
  }
  unsigned short bv = f2bf(acc);
  if (c < 128) {            // k part: kv[..., h*64+d]
    int h = c >> 6, dd = c & 63;
    kc_ws[(((b*2+h)*8 + (dd >> 3)) * 256 + j) * 8 + (dd & 7)] = bv;
  } else {                  // v part: kv[..., 128 + h*64+d]
    int c2 = c - 128;
    int h = c2 >> 6, dd = c2 & 63;
    vt_ws[((b*2+h)*64 + dd) * 256 + j] = bv;
  }
}

// ---------------- kernel 2: per-pixel features (shared across batch) ----------------
// writes t_ws[HW], qc_ws[HW][128] (bf16), h0_ws[HW][256], h1_ws[HW][256]
__global__ __launch_bounds__(256) void feat_kernel(
    const float* __restrict__ coords,
    const float* __restrict__ Bq, const float* __restrict__ Bl0, const float* __restrict__ Bl1,
    const float* __restrict__ qW, const float* __restrict__ qb,
    const float* __restrict__ toqW,
    const float* __restrict__ bwW0, const float* __restrict__ bwb0,
    const float* __restrict__ bwW1, const float* __restrict__ bwb1,
    float* __restrict__ t_ws, unsigned short* __restrict__ qc_ws,
    float* __restrict__ h0_ws, float* __restrict__ h1_ws)
{
  __shared__ __align__(16) float ffs[3][16][64];
  __shared__ __align__(16) float xq_s[16][256];
  int tid = threadIdx.x;
  int px0 = blockIdx.x * 16;

  // Fourier features: 3 mats * 16 px * 64 = 3072 values, 12 per thread
  for (int r = 0; r < 12; r++) {
    int v = r * 256 + tid;
    int mat = v >> 10;
    int p = (v >> 6) & 15;
    int f = v & 63;
    int fr = f & 31;
    const float* Bm = (mat == 0) ? Bq : (mat == 1 ? Bl0 : Bl1);
    float x = coords[(px0 + p) * 2 + 0];
    float y = coords[(px0 + p) * 2 + 1];
    float proj = 6.283185307179586f * (x * Bm[fr*2+0] + y * Bm[fr*2+1]);
    float s, cc;
    __sincosf(proj, &s, &cc);
    ffs[mat][p][f] = (f < 32) ? cc : s;
  }
  if (tid < 16) {
    float x = coords[(px0 + tid) * 2 + 0];
    float y = coords[(px0 + tid) * 2 + 1];
    int row = min(max((int)(x * 16.0f), 0), 15);
    int col = min(max((int)(y * 16.0f), 0), 15);
    t_ws[px0 + tid] = (float)(row * 16 + col) * (1.0f / 256.0f);
  }
  __syncthreads();

  // xq / h0 / h1: thread = output channel, 16 px register-blocked
  int c = tid;
  for (int mat = 0; mat < 3; mat++) {
    const float* W = (mat == 0) ? qW : (mat == 1 ? bwW0 : bwW1);
    float acc[16];
#pragma unroll
    for (int p = 0; p < 16; p++) acc[p] = 0.f;
    for (int i4 = 0; i4 < 16; i4++) {
      float w0 = W[(i4*4+0)*256 + c], w1 = W[(i4*4+1)*256 + c];
      float w2 = W[(i4*4+2)*256 + c], w3 = W[(i4*4+3)*256 + c];
#pragma unroll
      for (int p = 0; p < 16; p++) {
        float4 a = *(const float4*)&ffs[mat][p][i4*4];
        acc[p] += a.x*w0 + a.y*w1 + a.z*w2 + a.w*w3;
      }
    }
    if (mat == 0) {
      float bb = qb[c];
#pragma unroll
      for (int p = 0; p < 16; p++) xq_s[p][c] = fmaxf(acc[p] + bb, 0.f);
    } else if (mat == 1) {
      float bb = bwb0[c];
#pragma unroll
      for (int p = 0; p < 16; p++) h0_ws[(px0+p)*256 + c] = fmaxf(acc[p] + bb, 0.f);
    } else {
      float bb = bwb1[c];
#pragma unroll
      for (int p = 0; p < 16; p++) h1_ws[(px0+p)*256 + c] = fmaxf(acc[p] + bb, 0.f);
    }
  }
  __syncthreads();

  // q = xq @ toqW  (no bias), bf16 out. thread -> (half, d)
  {
    int d = tid & 127;
    int half = tid >> 7;
    float acc[8];
#pragma unroll
    for (int p = 0; p < 8; p++) acc[p] = 0.f;
    for (int i4 = 0; i4 < 64; i4++) {
      float w0 = toqW[(i4*4+0)*128 + d], w1 = toqW[(i4*4+1)*128 + d];
      float w2 = toqW[(i4*4+2)*128 + d], w3 = toqW[(i4*4+3)*128 + d];
#pragma unroll
      for (int p = 0; p < 8; p++) {
        float4 a = *(const float4*)&xq_s[half*8 + p][i4*4];
        acc[p] += a.x*w0 + a.y*w1 + a.z*w2 + a.w*w3;
      }
    }
#pragma unroll
    for (int p = 0; p < 8; p++)
      qc_ws[(px0 + half*8 + p) * 128 + d] = f2bf(acc[p]);
  }
}

// ---------------- kernel 3: cross attention with spatial bias ----------------
// block = 256 thr (4 waves), 16 px; wave register-blocks 4 pixels.
// V staged in LDS (padded rows), K coalesced from global (L1-hot), softmax via shfl.
__global__ __launch_bounds__(256) void attn_kernel(
    const unsigned short* __restrict__ kc_ws,
    const unsigned short* __restrict__ vt_ws,
    const unsigned short* __restrict__ qc_ws,
    const float* __restrict__ t_ws,
    float* __restrict__ o_ws)
{
  __shared__ __align__(16) unsigned short Vt_s[64][264];   // +8 bf16 pad: conflict-free b128
  __shared__ __align__(16) unsigned short attn_s[4][4][256];
  int b = blockIdx.y;
  int px0 = blockIdx.x * 16;
  int tid = threadIdx.x;
  int w = tid >> 6, ln = tid & 63;
  int pixb = px0 + w * 4;

  for (int h = 0; h < 2; h++) {
    __syncthreads();
    {  // stage V head h: 2048 uint4
      const uint4* src = (const uint4*)(vt_ws + ((size_t)(b*2+h) * 64) * 256);
      for (int r = 0; r < 8; r++) {
        int idx = r * 256 + tid;
        int dd = idx >> 5;
        int jc = (idx & 31) * 8;
        *(uint4*)&Vt_s[dd][jc] = src[idx];
      }
    }
    __syncthreads();

    float tp[4];
#pragma unroll
    for (int p = 0; p < 4; p++) tp[p] = t_ws[pixb + p];

    // sim = q.k  (lane = j mod 64, u = j/64), 4 px register-blocked
    float sim[4][4];
#pragma unroll
    for (int p = 0; p < 4; p++)
#pragma unroll
      for (int u = 0; u < 4; u++) sim[p][u] = 0.f;

    const uint4* kb = (const uint4*)kc_ws + (size_t)((b*2+h) * 8) * 256;
    for (int dblk = 0; dblk < 8; dblk++) {
      float qf[4][8];
#pragma unroll
      for (int p = 0; p < 4; p++) {
        uint4 qv = *((const uint4*)(qc_ws + (size_t)(pixb+p)*128 + h*64) + dblk);
        unpack8(qv, qf[p]);
      }
#pragma unroll
      for (int u = 0; u < 4; u++) {
        uint4 kv8 = kb[dblk * 256 + (ln + 64*u)];
        float kf[8];
        unpack8(kv8, kf);
#pragma unroll
        for (int p = 0; p < 4; p++)
#pragma unroll
          for (int e = 0; e < 8; e++) sim[p][u] += qf[p][e] * kf[e];
      }
    }

    // bias + softmax (per pixel, across the wave's 64 lanes * 4 u)
    float linv[4];
#pragma unroll
    for (int p = 0; p < 4; p++) {
      float sb[4], mx = -1e30f;
#pragma unroll
      for (int u = 0; u < 4; u++) {
        float j = (float)(ln + 64*u);
        float pos = (j + 0.5f) * (1.0f / 256.0f);
        float db = tp[p] - pos;
        sb[u] = sim[p][u] * 0.125f - 10.0f * db * db;
        mx = fmaxf(mx, sb[u]);
      }
#pragma unroll
      for (int s = 32; s; s >>= 1) mx = fmaxf(mx, __shfl_xor(mx, s, 64));
      float l = 0.f, ex[4];
#pragma unroll
      for (int u = 0; u < 4; u++) { ex[u] = __expf(sb[u] - mx); l += ex[u]; }
#pragma unroll
      for (int s = 32; s; s >>= 1) l += __shfl_xor(l, s, 64);
      linv[p] = 1.0f / l;
#pragma unroll
      for (int u = 0; u < 4; u++) attn_s[w][p][ln + 64*u] = f2bf(ex[u]);
    }
    __syncthreads();

    // o[d] = sum_j attn[j] * V[j][d]; lane = d
    float o[4] = {0.f, 0.f, 0.f, 0.f};
    for (int u = 0; u < 4; u++) {
#pragma unroll
      for (int jb = 0; jb < 8; jb++) {
        int jj = u * 64 + jb * 8;
        uint4 vv = *(const uint4*)&Vt_s[ln][jj];
        float vf[8];
        unpack8(vv, vf);
#pragma unroll
        for (int p = 0; p < 4; p++) {
          uint4 av = *(const uint4*)&attn_s[w][p][jj];
          float af[8];
          unpack8(av, af);
#pragma unroll
          for (int e = 0; e < 8; e++) o[p] += af[e] * vf[e];
        }
      }
    }
#pragma unroll
    for (int p = 0; p < 4; p++)
      o_ws[((size_t)b * kHW + pixb + p) * 128 + h*64 + ln] = o[p] * linv[p];
  }
}

// ---------------- kernel 4: MLP chain: mod -> m0,m1 -> hv1 -> out ----------------
__global__ __launch_bounds__(256) void mlp_kernel(
    const float* __restrict__ o_ws,
    const float* __restrict__ h0_ws, const float* __restrict__ h1_ws,
    const float* __restrict__ tooW, const float* __restrict__ toob,
    const float* __restrict__ modW0, const float* __restrict__ modb0,
    const float* __restrict__ modW1, const float* __restrict__ modb1,
    const float* __restrict__ hvW0, const float* __restrict__ hvb0,
    const float* __restrict__ outW0, const float* __restrict__ outb0,
    const float* __restrict__ outW1, const float* __restrict__ outb1,
    float* __restrict__ dout)
{
  __shared__ __align__(16) float o_s[16][128];   // o tile, later reused as reduction scratch
  __shared__ __align__(16) float T1[16][256];    // mod, then S = m0+m1
  __shared__ __align__(16) float T2[16][256];    // m0 (= hv0)
  __shared__ __align__(16) float T3[16][256];    // hv1
  int b = blockIdx.y;
  int px0 = blockIdx.x * 16;
  int tid = threadIdx.x;

  {
    const float4* src = (const float4*)(o_ws + ((size_t)b * kHW + px0) * 128);
    float4* dst = (float4*)&o_s[0][0];
    dst[tid] = src[tid];
    dst[256 + tid] = src[256 + tid];
  }
  __syncthreads();

  int c = tid;
  // mod = o @ tooW + toob
  {
    float acc[16];
#pragma unroll
    for (int p = 0; p < 16; p++) acc[p] = 0.f;
    for (int i4 = 0; i4 < 32; i4++) {
      float w0 = tooW[(i4*4+0)*256 + c], w1 = tooW[(i4*4+1)*256 + c];
      float w2 = tooW[(i4*4+2)*256 + c], w3 = tooW[(i4*4+3)*256 + c];
#pragma unroll
      for (int p = 0; p < 16; p++) {
        float4 a = *(const float4*)&o_s[p][i4*4];
        acc[p] += a.x*w0 + a.y*w1 + a.z*w2 + a.w*w3;
      }
    }
    float bb = toob[c];
#pragma unroll
    for (int p = 0; p < 16; p++) T1[p][c] = acc[p] + bb;
  }
  __syncthreads();

  float m0v[16];
  // m0 = relu(h0 + mod@modW0 + modb0)
  {
    float acc[16];
#pragma unroll
    for (int p = 0; p < 16; p++) acc[p] = 0.f;
    for (int i4 = 0; i4 < 64; i4++) {
      float w0 = modW0[(i4*4+0)*256 + c], w1 = modW0[(i4*4+1)*256 + c];
      float w2 = modW0[(i4*4+2)*256 + c], w3 = modW0[(i4*4+3)*256 + c];
#pragma unroll
      for (int p = 0; p < 16; p++) {
        float4 a = *(const float4*)&T1[p][i4*4];
        acc[p] += a.x*w0 + a.y*w1 + a.z*w2 + a.w*w3;
      }
    }
    float bb = modb0[c];
#pragma unroll
    for (int p = 0; p < 16; p++) {
      m0v[p] = fmaxf(acc[p] + bb + h0_ws[(px0+p)*256 + c], 0.f);
      T2[p][c] = m0v[p];
    }
  }
  // m1 (still reads T1=mod), then S = m0 + m1
  float Sv[16];
  {
    float acc[16];
#pragma unroll
    for (int p = 0; p < 16; p++) acc[p] = 0.f;
    for (int i4 = 0; i4 < 64; i4++) {
      float w0 = modW1[(i4*4+0)*256 + c], w1 = modW1[(i4*4+1)*256 + c];
      float w2 = modW1[(i4*4+2)*256 + c], w3 = modW1[(i4*4+3)*256 + c];
#pragma unroll
      for (int p = 0; p < 16; p++) {
        float4 a = *(const float4*)&T1[p][i4*4];
        acc[p] += a.x*w0 + a.y*w1 + a.z*w2 + a.w*w3;
      }
    }
    float bb = modb1[c];
#pragma unroll
    for (int p = 0; p < 16; p++)
      Sv[p] = m0v[p] + fmaxf(acc[p] + bb + h1_ws[(px0+p)*256 + c], 0.f);
  }
  __syncthreads();           // all threads done reading T1 (mod)
#pragma unroll
  for (int p = 0; p < 16; p++) T1[p][c] = Sv[p];
  __syncthreads();

  // hv1 = relu(S @ hvW0 + hvb0)
  {
    float acc[16];
#pragma unroll
    for (int p = 0; p < 16; p++) acc[p] = 0.f;
    for (int i4 = 0; i4 < 64; i4++) {
      float w0 = hvW0[(i4*4+0)*256 + c], w1 = hvW0[(i4*4+1)*256 + c];
      float w2 = hvW0[(i4*4+2)*256 + c], w3 = hvW0[(i4*4+3)*256 + c];
#pragma unroll
      for (int p = 0; p < 16; p++) {
        float4 a = *(const float4*)&T1[p][i4*4];
        acc[p] += a.x*w0 + a.y*w1 + a.z*w2 + a.w*w3;
      }
    }
    float bb = hvb0[c];
#pragma unroll
    for (int p = 0; p < 16; p++) T3[p][c] = fmaxf(acc[p] + bb, 0.f);
  }
  __syncthreads();

  // out[p][k] = sum_c T2*outW0 + T3*outW1 (+biases); two-level reduce
  {
    int p = tid >> 4, r = tid & 15;
    float part0 = 0.f, part1 = 0.f, part2 = 0.f;
    for (int i = 0; i < 16; i++) {
      int cc = r * 16 + i;
      float a = T2[p][cc], hh = T3[p][cc];
      part0 += a * outW0[cc*3+0] + hh * outW1[cc*3+0];
      part1 += a * outW0[cc*3+1] + hh * outW1[cc*3+1];
      part2 += a * outW0[cc*3+2] + hh * outW1[cc*3+2];
    }
    float* red = &o_s[0][0];
    red[(p*16+r)*3+0] = part0;
    red[(p*16+r)*3+1] = part1;
    red[(p*16+r)*3+2] = part2;
  }
  __syncthreads();
  if (tid < 48) {
    int p = tid / 3, k = tid % 3;
    const float* red = &o_s[0][0];
    float s = outb0[k] + outb1[k];
    for (int r = 0; r < 16; r++) s += red[(p*16+r)*3 + k];
    dout[((size_t)b * kHW + px0 + p) * 3 + k] = s;
  }
}

// ---------------- launch ----------------
extern "C" void kernel_launch(void* const* d_in, const int* in_sizes, int n_in,
                              void* d_out, int out_size, void* d_ws, size_t ws_size,
                              hipStream_t stream) {
  const float* coords = (const float*)d_in[0];
  const float* tokens = (const float*)d_in[1];
  const float* Bq     = (const float*)d_in[2];
  const float* Bl0    = (const float*)d_in[3];
  const float* Bl1    = (const float*)d_in[4];
  const float* qW     = (const float*)d_in[5];
  const float* qb     = (const float*)d_in[6];
  const float* toqW   = (const float*)d_in[7];
  const float* tokvW  = (const float*)d_in[8];
  const float* tooW   = (const float*)d_in[9];
  const float* toob   = (const float*)d_in[10];
  const float* bwW0   = (const float*)d_in[11];
  const float* bwb0   = (const float*)d_in[12];
  const float* bwW1   = (const float*)d_in[13];
  const float* bwb1   = (const float*)d_in[14];
  const float* modW0  = (const float*)d_in[15];
  const float* modb0  = (const float*)d_in[16];
  const float* modW1  = (const float*)d_in[17];
  const float* modb1  = (const float*)d_in[18];
  const float* hvW0   = (const float*)d_in[19];
  const float* hvb0   = (const float*)d_in[20];
  const float* outW0  = (const float*)d_in[21];
  const float* outb0  = (const float*)d_in[22];
  const float* outW1  = (const float*)d_in[23];
  const float* outb1  = (const float*)d_in[24];

  char* ws = (char*)d_ws;
  float*          t_ws  = (float*)(ws + 0);               //   64 KB
  unsigned short* qc_ws = (unsigned short*)(ws + 65536);  //    4 MB
  float*          h0_ws = (float*)(ws + 4259840);         //   16 MB
  float*          h1_ws = (float*)(ws + 21037056);        //   16 MB
  unsigned short* kc_ws = (unsigned short*)(ws + 37814272); // 256 KB
  unsigned short* vt_ws = (unsigned short*)(ws + 38076416); // 256 KB
  float*          o_ws  = (float*)(ws + 38338560);        //   32 MB  (total ~68.6 MB)

  feat_kernel<<<dim3(kHW / 16), 256, 0, stream>>>(
      coords, Bq, Bl0, Bl1, qW, qb, toqW, bwW0, bwb0, bwW1, bwb1,
      t_ws, qc_ws, h0_ws, h1_ws);
  kv_kernel<<<dim3(kM, kB), 256, 0, stream>>>(tokens, tokvW, kc_ws, vt_ws);
  attn_kernel<<<dim3(kHW / 16, kB), 256, 0, stream>>>(kc_ws, vt_ws, qc_ws, t_ws, o_ws);
  mlp_kernel<<<dim3(kHW / 16, kB), 256, 0, stream>>>(
      o_ws, h0_ws, h1_ws, tooW, toob, modW0, modb0, modW1, modb1,
      hvW0, hvb0, outW0, outb0, outW1, outb1, (float*)d_out);
}

// Round 3
// 607.518 us; speedup vs baseline: 1.7431x; 1.7431x over previous
//
#include <hip/hip_runtime.h>
#include <stdint.h>

constexpr int kHW    = 16384;   // 128*128 pixels (grid shared across batch)
constexpr int kB     = 4;
constexpr int kM     = 256;     // tokens

typedef __attribute__((ext_vector_type(8))) short short8;   // 8 bf16 (4 VGPRs)
typedef __attribute__((ext_vector_type(4))) float f32x4;    // MFMA accum

// ---------------- helpers ----------------
__device__ __forceinline__ unsigned short f2bf(float f) {
  unsigned u = __float_as_uint(f);
  unsigned r = (u + 0x7fffu + ((u >> 16) & 1u)) >> 16;
  return (unsigned short)r;
}
__device__ __forceinline__ float bf2f(unsigned short u) {
  return __uint_as_float(((unsigned)u) << 16);
}
__device__ __forceinline__ void unpack8(uint4 v, float* f) {
  f[0] = __uint_as_float(v.x << 16); f[1] = __uint_as_float(v.x & 0xffff0000u);
  f[2] = __uint_as_float(v.y << 16); f[3] = __uint_as_float(v.y & 0xffff0000u);
  f[4] = __uint_as_float(v.z << 16); f[5] = __uint_as_float(v.z & 0xffff0000u);
  f[6] = __uint_as_float(v.w << 16); f[7] = __uint_as_float(v.w & 0xffff0000u);
}

// ---------------- kernel 0: weight prep (transpose + hi/lo bf16 split) ----------------
// Wt layout: hi[n][k] at [0, 256*K), lo[n][k] at [256*K, 512*K).
__global__ __launch_bounds__(256) void wprep_kernel(
    const float* __restrict__ tooW, const float* __restrict__ modW0,
    const float* __restrict__ modW1, const float* __restrict__ hvW0,
    unsigned short* __restrict__ tooWt, unsigned short* __restrict__ modW0t,
    unsigned short* __restrict__ modW1t, unsigned short* __restrict__ hvW0t)
{
  int m = blockIdx.x, tid = threadIdx.x;
  const float* W = (m == 0) ? tooW : (m == 1 ? modW0 : (m == 2 ? modW1 : hvW0));
  unsigned short* Wt = (m == 0) ? tooWt : (m == 1 ? modW0t : (m == 2 ? modW1t : hvW0t));
  int K = (m == 0) ? 128 : 256;
  for (int kb = 0; kb < K / 8; kb++) {
    short8 hv, lv;
#pragma unroll
    for (int i = 0; i < 8; i++) {
      float v = W[(kb * 8 + i) * 256 + tid];    // coalesced across tid
      unsigned short hi = f2bf(v);
      float r = v - bf2f(hi);
      hv[i] = (short)hi;
      lv[i] = (short)f2bf(r);
    }
    *(short8*)&Wt[tid * K + kb * 8] = hv;
    *(short8*)&Wt[256 * K + tid * K + kb * 8] = lv;
  }
}

// ---------------- kernel 1: kv = tokens @ tokvW -> K (chunked) + V (transposed), bf16 ----------------
__global__ __launch_bounds__(256) void kv_kernel(
    const float* __restrict__ tokens, const float* __restrict__ tokvW,
    unsigned short* __restrict__ kc_ws, unsigned short* __restrict__ vt_ws)
{
  __shared__ __align__(16) float tok[256];
  int b = blockIdx.y, j = blockIdx.x, c = threadIdx.x;
  tok[c] = tokens[(b * kM + j) * 256 + c];
  __syncthreads();
  float acc = 0.f;
  for (int i4 = 0; i4 < 64; i4++) {
    float4 t4 = *(const float4*)&tok[i4 * 4];
    acc += t4.x * tokvW[(i4*4+0)*256 + c] + t4.y * tokvW[(i4*4+1)*256 + c]
         + t4.z * tokvW[(i4*4+2)*256 + c] + t4.w * tokvW[(i4*4+3)*256 + c];
  }
  unsigned short bv = f2bf(acc);
  if (c < 128) {
    int h = c >> 6, dd = c & 63;
    kc_ws[(((b*2+h)*8 + (dd >> 3)) * 256 + j) * 8 + (dd & 7)] = bv;
  } else {
    int c2 = c - 128;
    int h = c2 >> 6, dd = c2 & 63;
    vt_ws[((b*2+h)*64 + dd) * 256 + j] = bv;
  }
}

// ---------------- kernel 2: per-pixel features (shared across batch) ----------------
// h0/h1 kept fp32 for precision; q bf16 for the attention dot.
__global__ __launch_bounds__(256) void feat_kernel(
    const float* __restrict__ coords,
    const float* __restrict__ Bq, const float* __restrict__ Bl0, const float* __restrict__ Bl1,
    const float* __restrict__ qW, const float* __restrict__ qb,
    const float* __restrict__ toqW,
    const float* __restrict__ bwW0, const float* __restrict__ bwb0,
    const float* __restrict__ bwW1, const float* __restrict__ bwb1,
    float* __restrict__ t_ws, unsigned short* __restrict__ qc_ws,
    float* __restrict__ h0_ws, float* __restrict__ h1_ws)
{
  __shared__ __align__(16) float ffs[3][16][64];
  __shared__ __align__(16) float xq_s[16][256];
  int tid = threadIdx.x;
  int px0 = blockIdx.x * 16;

  for (int r = 0; r < 12; r++) {
    int v = r * 256 + tid;
    int mat = v >> 10;
    int p = (v >> 6) & 15;
    int f = v & 63;
    int fr = f & 31;
    const float* Bm = (mat == 0) ? Bq : (mat == 1 ? Bl0 : Bl1);
    float x = coords[(px0 + p) * 2 + 0];
    float y = coords[(px0 + p) * 2 + 1];
    float proj = 6.283185307179586f * (x * Bm[fr*2+0] + y * Bm[fr*2+1]);
    float s, cc;
    __sincosf(proj, &s, &cc);
    ffs[mat][p][f] = (f < 32) ? cc : s;
  }
  if (tid < 16) {
    float x = coords[(px0 + tid) * 2 + 0];
    float y = coords[(px0 + tid) * 2 + 1];
    int row = min(max((int)(x * 16.0f), 0), 15);
    int col = min(max((int)(y * 16.0f), 0), 15);
    t_ws[px0 + tid] = (float)(row * 16 + col) * (1.0f / 256.0f);
  }
  __syncthreads();

  int c = tid;
  for (int mat = 0; mat < 3; mat++) {
    const float* W = (mat == 0) ? qW : (mat == 1 ? bwW0 : bwW1);
    float acc[16];
#pragma unroll
    for (int p = 0; p < 16; p++) acc[p] = 0.f;
    for (int i4 = 0; i4 < 16; i4++) {
      float w0 = W[(i4*4+0)*256 + c], w1 = W[(i4*4+1)*256 + c];
      float w2 = W[(i4*4+2)*256 + c], w3 = W[(i4*4+3)*256 + c];
#pragma unroll
      for (int p = 0; p < 16; p++) {
        float4 a = *(const float4*)&ffs[mat][p][i4*4];
        acc[p] += a.x*w0 + a.y*w1 + a.z*w2 + a.w*w3;
      }
    }
    if (mat == 0) {
      float bb = qb[c];
#pragma unroll
      for (int p = 0; p < 16; p++) xq_s[p][c] = fmaxf(acc[p] + bb, 0.f);
    } else if (mat == 1) {
      float bb = bwb0[c];
#pragma unroll
      for (int p = 0; p < 16; p++) h0_ws[(px0+p)*256 + c] = fmaxf(acc[p] + bb, 0.f);
    } else {
      float bb = bwb1[c];
#pragma unroll
      for (int p = 0; p < 16; p++) h1_ws[(px0+p)*256 + c] = fmaxf(acc[p] + bb, 0.f);
    }
  }
  __syncthreads();

  {
    int d = tid & 127;
    int half = tid >> 7;
    float acc[8];
#pragma unroll
    for (int p = 0; p < 8; p++) acc[p] = 0.f;
    for (int i4 = 0; i4 < 64; i4++) {
      float w0 = toqW[(i4*4+0)*128 + d], w1 = toqW[(i4*4+1)*128 + d];
      float w2 = toqW[(i4*4+2)*128 + d], w3 = toqW[(i4*4+3)*128 + d];
#pragma unroll
      for (int p = 0; p < 8; p++) {
        float4 a = *(const float4*)&xq_s[half*8 + p][i4*4];
        acc[p] += a.x*w0 + a.y*w1 + a.z*w2 + a.w*w3;
      }
    }
#pragma unroll
    for (int p = 0; p < 8; p++)
      qc_ws[(px0 + half*8 + p) * 128 + d] = f2bf(acc[p]);
  }
}

// ---------------- kernel 3: cross attention with spatial bias (R1-proven) ----------------
__global__ __launch_bounds__(256) void attn_kernel(
    const unsigned short* __restrict__ kc_ws,
    const unsigned short* __restrict__ vt_ws,
    const unsigned short* __restrict__ qc_ws,
    const float* __restrict__ t_ws,
    unsigned short* __restrict__ o_bf)
{
  __shared__ __align__(16) unsigned short Vt_s[64][264];
  __shared__ __align__(16) unsigned short attn_s[4][4][256];
  int b = blockIdx.y;
  int px0 = blockIdx.x * 16;
  int tid = threadIdx.x;
  int w = tid >> 6, ln = tid & 63;
  int pixb = px0 + w * 4;

  for (int h = 0; h < 2; h++) {
    __syncthreads();
    {
      const uint4* src = (const uint4*)(vt_ws + ((size_t)(b*2+h) * 64) * 256);
      for (int r = 0; r < 8; r++) {
        int idx = r * 256 + tid;
        int dd = idx >> 5;
        int jc = (idx & 31) * 8;
        *(uint4*)&Vt_s[dd][jc] = src[idx];
      }
    }
    __syncthreads();

    float tp[4];
#pragma unroll
    for (int p = 0; p < 4; p++) tp[p] = t_ws[pixb + p];

    float sim[4][4];
#pragma unroll
    for (int p = 0; p < 4; p++)
#pragma unroll
      for (int u = 0; u < 4; u++) sim[p][u] = 0.f;

    const uint4* kb = (const uint4*)kc_ws + (size_t)((b*2+h) * 8) * 256;
    for (int dblk = 0; dblk < 8; dblk++) {
      float qf[4][8];
#pragma unroll
      for (int p = 0; p < 4; p++) {
        uint4 qv = *((const uint4*)(qc_ws + (size_t)(pixb+p)*128 + h*64) + dblk);
        unpack8(qv, qf[p]);
      }
#pragma unroll
      for (int u = 0; u < 4; u++) {
        uint4 kv8 = kb[dblk * 256 + (ln + 64*u)];
        float kf[8];
        unpack8(kv8, kf);
#pragma unroll
        for (int p = 0; p < 4; p++)
#pragma unroll
          for (int e = 0; e < 8; e++) sim[p][u] += qf[p][e] * kf[e];
      }
    }

    float linv[4];
#pragma unroll
    for (int p = 0; p < 4; p++) {
      float sb[4], mx = -1e30f;
#pragma unroll
      for (int u = 0; u < 4; u++) {
        float j = (float)(ln + 64*u);
        float pos = (j + 0.5f) * (1.0f / 256.0f);
        float db = tp[p] - pos;
        sb[u] = sim[p][u] * 0.125f - 10.0f * db * db;
        mx = fmaxf(mx, sb[u]);
      }
#pragma unroll
      for (int s = 32; s; s >>= 1) mx = fmaxf(mx, __shfl_xor(mx, s, 64));
      float l = 0.f, ex[4];
#pragma unroll
      for (int u = 0; u < 4; u++) { ex[u] = __expf(sb[u] - mx); l += ex[u]; }
#pragma unroll
      for (int s = 32; s; s >>= 1) l += __shfl_xor(l, s, 64);
      linv[p] = 1.0f / l;
#pragma unroll
      for (int u = 0; u < 4; u++) attn_s[w][p][ln + 64*u] = f2bf(ex[u]);
    }
    __syncthreads();

    float o[4] = {0.f, 0.f, 0.f, 0.f};
    for (int u = 0; u < 4; u++) {
#pragma unroll
      for (int jb = 0; jb < 8; jb++) {
        int jj = u * 64 + jb * 8;
        uint4 vv = *(const uint4*)&Vt_s[ln][jj];
        float vf[8];
        unpack8(vv, vf);
#pragma unroll
        for (int p = 0; p < 4; p++) {
          uint4 av = *(const uint4*)&attn_s[w][p][jj];
          float af[8];
          unpack8(av, af);
#pragma unroll
          for (int e = 0; e < 8; e++) o[p] += af[e] * vf[e];
        }
      }
    }
#pragma unroll
    for (int p = 0; p < 4; p++)
      o_bf[((size_t)b * kHW + pixb + p) * 128 + h*64 + ln] = f2bf(o[p] * linv[p]);
  }
}

// ---------------- kernel 4: MFMA MLP chain (hi/lo split weights, fp32 carries) ----------------
// Block: 8 pixels x 4 batch = 32 rows; 4 waves, wave w -> cols [w*64, w*64+64).
// C layout (m89-verified): col = ln&15, row = (ln>>4)*4 + reg.
constexpr int kPitch  = 264;   // bf16 LDS pitch
constexpr int kHPitch = 260;   // fp32 LDS pitch for h-tiles (16B-aligned rows)

template <int KD>
__device__ __forceinline__ void gemm_block(
    const unsigned short* abuf, const unsigned short* wt,
    f32x4* acc /*[2*4]*/, int r, int q)
{
#pragma unroll
  for (int ks = 0; ks < KD / 32; ks++) {
    int koff = ks * 32 + q * 8;
    short8 bh[4], bl[4];
#pragma unroll
    for (int nt = 0; nt < 4; nt++) {
      bh[nt] = *(const short8*)(wt + (nt * 16 + r) * KD + koff);
      bl[nt] = *(const short8*)(wt + 256 * KD + (nt * 16 + r) * KD + koff);
    }
#pragma unroll
    for (int mt = 0; mt < 2; mt++) {
      short8 a = *(const short8*)(abuf + (mt * 16 + r) * kPitch + koff);
#pragma unroll
      for (int nt = 0; nt < 4; nt++) {
        acc[mt * 4 + nt] = __builtin_amdgcn_mfma_f32_16x16x32_bf16(a, bh[nt], acc[mt * 4 + nt], 0, 0, 0);
        acc[mt * 4 + nt] = __builtin_amdgcn_mfma_f32_16x16x32_bf16(a, bl[nt], acc[mt * 4 + nt], 0, 0, 0);
      }
    }
  }
}

__global__ __launch_bounds__(256, 2) void mlp_kernel(
    const unsigned short* __restrict__ o_bf,
    const float* __restrict__ h0_ws, const float* __restrict__ h1_ws,
    const unsigned short* __restrict__ tooWt, const float* __restrict__ toob,
    const unsigned short* __restrict__ modW0t, const float* __restrict__ modb0,
    const unsigned short* __restrict__ modW1t, const float* __restrict__ modb1,
    const unsigned short* __restrict__ hvW0t, const float* __restrict__ hvb0,
    const float* __restrict__ outW0, const float* __restrict__ outb0,
    const float* __restrict__ outW1, const float* __restrict__ outb1,
    float* __restrict__ dout)
{
  __shared__ __align__(16) unsigned short buf0[32 * kPitch];  // o, then m0
  __shared__ __align__(16) unsigned short buf1[32 * kPitch];  // mod, then S
  __shared__ __align__(16) float hbuf[8 * kHPitch];           // h0 (fp32), then h1
  __shared__ __align__(16) float scratch[32 * 3 * 4];         // out partials [row][k][wave]

  int tid = threadIdx.x;
  int px0 = blockIdx.x * 8;
  int w = tid >> 6, ln = tid & 63;
  int c = ln & 15, q = ln >> 4;

  // ---- stage o (bf16) and h0 (fp32) ----
#pragma unroll
  for (int i = 0; i < 2; i++) {
    int idx = i * 256 + tid;              // 512 x uint4 (8 bf16)
    int r = idx >> 4, c8 = (idx & 15) * 8;
    int b = r >> 3, px = px0 + (r & 7);
    uint4 v = *(const uint4*)(o_bf + ((size_t)(b * kHW + px)) * 128 + c8);
    *(uint4*)&buf0[r * kPitch + c8] = v;
  }
#pragma unroll
  for (int i = 0; i < 2; i++) {
    int idx = i * 256 + tid;              // 512 x float4
    int p = idx >> 6, c4 = (idx & 63) * 4;
    float4 v = *(const float4*)(h0_ws + ((size_t)(px0 + p)) * 256 + c4);
    *(float4*)&hbuf[p * kHPitch + c4] = v;
  }
  __syncthreads();

  f32x4 acc[8];
  const f32x4 zero4 = {0.f, 0.f, 0.f, 0.f};

  // ---- P1: mod = o @ tooW + toob -> buf1 (bf16) ----
#pragma unroll
  for (int i = 0; i < 8; i++) acc[i] = zero4;
  gemm_block<128>(buf0, tooWt + (size_t)w * 64 * 128, acc, c, q);
  __syncthreads();                         // all buf0 (o) reads done
  {
    float bias[4];
#pragma unroll
    for (int nt = 0; nt < 4; nt++) bias[nt] = toob[w * 64 + nt * 16 + c];
#pragma unroll
    for (int mt = 0; mt < 2; mt++)
#pragma unroll
      for (int nt = 0; nt < 4; nt++)
#pragma unroll
        for (int rg = 0; rg < 4; rg++) {
          int row = mt * 16 + q * 4 + rg, col = w * 64 + nt * 16 + c;
          buf1[row * kPitch + col] = f2bf(acc[mt * 4 + nt][rg] + bias[nt]);
        }
  }
  __syncthreads();                         // buf1 (mod) ready

  // ---- P2: m0 = relu(h0 + mod @ modW0 + b) -> fp32 regs + buf0 (bf16) ----
  float m0f[8][4];
#pragma unroll
  for (int i = 0; i < 8; i++) acc[i] = zero4;
  gemm_block<256>(buf1, modW0t + (size_t)w * 64 * 256, acc, c, q);
  {
    float bias[4];
#pragma unroll
    for (int nt = 0; nt < 4; nt++) bias[nt] = modb0[w * 64 + nt * 16 + c];
#pragma unroll
    for (int nt = 0; nt < 4; nt++)
#pragma unroll
      for (int rg = 0; rg < 4; rg++) {
        int col = w * 64 + nt * 16 + c;
        float hv = hbuf[((q * 4 + rg) & 7) * kHPitch + col];
#pragma unroll
        for (int mt = 0; mt < 2; mt++) {
          int row = mt * 16 + q * 4 + rg;
          float v = fmaxf(acc[mt * 4 + nt][rg] + bias[nt] + hv, 0.f);
          m0f[mt * 4 + nt][rg] = v;
          buf0[row * kPitch + col] = f2bf(v);   // not needed downstream as bf16 GEMM input? (kept: unused)
        }
      }
  }
  __syncthreads();                         // hbuf (h0) consumed

  // ---- P3: stage h1; m1 = relu(h1 + mod @ modW1 + b); S = m0 + m1 -> buf1 (bf16) ----
#pragma unroll
  for (int i = 0; i < 2; i++) {
    int idx = i * 256 + tid;
    int p = idx >> 6, c4 = (idx & 63) * 4;
    float4 v = *(const float4*)(h1_ws + ((size_t)(px0 + p)) * 256 + c4);
    *(float4*)&hbuf[p * kHPitch + c4] = v;
  }
#pragma unroll
  for (int i = 0; i < 8; i++) acc[i] = zero4;
  gemm_block<256>(buf1, modW1t + (size_t)w * 64 * 256, acc, c, q);
  __syncthreads();                         // h1 staged AND all mod reads done
  {
    float bias[4];
#pragma unroll
    for (int nt = 0; nt < 4; nt++) bias[nt] = modb1[w * 64 + nt * 16 + c];
#pragma unroll
    for (int nt = 0; nt < 4; nt++)
#pragma unroll
      for (int rg = 0; rg < 4; rg++) {
        int col = w * 64 + nt * 16 + c;
        float hv = hbuf[((q * 4 + rg) & 7) * kHPitch + col];
#pragma unroll
        for (int mt = 0; mt < 2; mt++) {
          int row = mt * 16 + q * 4 + rg;
          float v = m0f[mt * 4 + nt][rg] + fmaxf(acc[mt * 4 + nt][rg] + bias[nt] + hv, 0.f);
          buf1[row * kPitch + col] = f2bf(v);
        }
      }
  }
  __syncthreads();                         // buf1 = S

  // ---- P4: hv1 = relu(S @ hvW0 + b) -> fp32 regs only ----
#pragma unroll
  for (int i = 0; i < 8; i++) acc[i] = zero4;
  gemm_block<256>(buf1, hvW0t + (size_t)w * 64 * 256, acc, c, q);
  float hv1f[8][4];
  {
    float bias[4];
#pragma unroll
    for (int nt = 0; nt < 4; nt++) bias[nt] = hvb0[w * 64 + nt * 16 + c];
#pragma unroll
    for (int i = 0; i < 8; i++)
#pragma unroll
      for (int rg = 0; rg < 4; rg++)
        hv1f[i][rg] = fmaxf(acc[i][rg] + bias[i & 3], 0.f);
  }

  // ---- P5: out = hv0 @ outW0 + hv1 @ outW1 + b, full fp32 ----
  {
    float w0v[4][3], w1v[4][3];
#pragma unroll
    for (int nt = 0; nt < 4; nt++) {
      int col = w * 64 + nt * 16 + c;
#pragma unroll
      for (int k = 0; k < 3; k++) {
        w0v[nt][k] = outW0[col * 3 + k];
        w1v[nt][k] = outW1[col * 3 + k];
      }
    }
#pragma unroll
    for (int mt = 0; mt < 2; mt++)
#pragma unroll
      for (int rg = 0; rg < 4; rg++) {
        float pk[3] = {0.f, 0.f, 0.f};
#pragma unroll
        for (int nt = 0; nt < 4; nt++)
#pragma unroll
          for (int k = 0; k < 3; k++)
            pk[k] += m0f[mt * 4 + nt][rg] * w0v[nt][k]
                   + hv1f[mt * 4 + nt][rg] * w1v[nt][k];
        // butterfly over c (lanes q*16 + 0..15)
#pragma unroll
        for (int k = 0; k < 3; k++) {
#pragma unroll
          for (int s = 1; s < 16; s <<= 1) pk[k] += __shfl_xor(pk[k], s, 64);
        }
        if (c == 0) {
          int row = mt * 16 + q * 4 + rg;
#pragma unroll
          for (int k = 0; k < 3; k++) scratch[(row * 3 + k) * 4 + w] = pk[k];
        }
      }
  }
  __syncthreads();

  if (tid < 96) {
    int row = tid / 3, k = tid % 3;
    int b = row >> 3, px = px0 + (row & 7);
    float s = outb0[k] + outb1[k];
#pragma unroll
    for (int ww = 0; ww < 4; ww++) s += scratch[(row * 3 + k) * 4 + ww];
    dout[((size_t)b * kHW + px) * 3 + k] = s;
  }
}

// ---------------- launch ----------------
extern "C" void kernel_launch(void* const* d_in, const int* in_sizes, int n_in,
                              void* d_out, int out_size, void* d_ws, size_t ws_size,
                              hipStream_t stream) {
  const float* coords = (const float*)d_in[0];
  const float* tokens = (const float*)d_in[1];
  const float* Bq     = (const float*)d_in[2];
  const float* Bl0    = (const float*)d_in[3];
  const float* Bl1    = (const float*)d_in[4];
  const float* qW     = (const float*)d_in[5];
  const float* qb     = (const float*)d_in[6];
  const float* toqW   = (const float*)d_in[7];
  const float* tokvW  = (const float*)d_in[8];
  const float* tooW   = (const float*)d_in[9];
  const float* toob   = (const float*)d_in[10];
  const float* bwW0   = (const float*)d_in[11];
  const float* bwb0   = (const float*)d_in[12];
  const float* bwW1   = (const float*)d_in[13];
  const float* bwb1   = (const float*)d_in[14];
  const float* modW0  = (const float*)d_in[15];
  const float* modb0  = (const float*)d_in[16];
  const float* modW1  = (const float*)d_in[17];
  const float* modb1  = (const float*)d_in[18];
  const float* hvW0   = (const float*)d_in[19];
  const float* hvb0   = (const float*)d_in[20];
  const float* outW0  = (const float*)d_in[21];
  const float* outb0  = (const float*)d_in[22];
  const float* outW1  = (const float*)d_in[23];
  const float* outb1  = (const float*)d_in[24];

  char* ws = (char*)d_ws;
  float*          t_ws   = (float*)(ws + 0);                  //   64 KB
  unsigned short* qc_ws  = (unsigned short*)(ws + 65536);     //    4 MB
  float*          h0_ws  = (float*)(ws + 4259840);            //   16 MB
  float*          h1_ws  = (float*)(ws + 21037056);           //   16 MB
  unsigned short* o_bf   = (unsigned short*)(ws + 37814272);  //   16 MB
  unsigned short* kc_ws  = (unsigned short*)(ws + 54591488);  //  256 KB
  unsigned short* vt_ws  = (unsigned short*)(ws + 54853632);  //  256 KB
  unsigned short* tooWt  = (unsigned short*)(ws + 55115776);  //  128 KB (hi+lo)
  unsigned short* modW0t = (unsigned short*)(ws + 55246848);  //  256 KB
  unsigned short* modW1t = (unsigned short*)(ws + 55508992);  //  256 KB
  unsigned short* hvW0t  = (unsigned short*)(ws + 55771136);  //  256 KB

  wprep_kernel<<<dim3(4), 256, 0, stream>>>(
      tooW, modW0, modW1, hvW0, tooWt, modW0t, modW1t, hvW0t);
  feat_kernel<<<dim3(kHW / 16), 256, 0, stream>>>(
      coords, Bq, Bl0, Bl1, qW, qb, toqW, bwW0, bwb0, bwW1, bwb1,
      t_ws, qc_ws, h0_ws, h1_ws);
  kv_kernel<<<dim3(kM, kB), 256, 0, stream>>>(tokens, tokvW, kc_ws, vt_ws);
  attn_kernel<<<dim3(kHW / 16, kB), 256, 0, stream>>>(kc_ws, vt_ws, qc_ws, t_ws, o_bf);
  mlp_kernel<<<dim3(kHW / 8), 256, 0, stream>>>(
      o_bf, h0_ws, h1_ws, tooWt, toob, modW0t, modb0, modW1t, modb1,
      hvW0t, hvb0, outW0, outb0, outW1, outb1, (float*)d_out);
}

// Round 4
// 449.047 us; speedup vs baseline: 2.3582x; 1.3529x over previous
//
#include <hip/hip_runtime.h>
#include <stdint.h>

constexpr int kHW    = 16384;   // 128*128 pixels (grid shared across batch)
constexpr int kB     = 4;
constexpr int kM     = 256;     // tokens

typedef __attribute__((ext_vector_type(8))) short short8;   // 8 bf16 (4 VGPRs)
typedef __attribute__((ext_vector_type(4))) float f32x4;    // MFMA accum

// ---------------- helpers ----------------
__device__ __forceinline__ unsigned short f2bf(float f) {
  unsigned u = __float_as_uint(f);
  unsigned r = (u + 0x7fffu + ((u >> 16) & 1u)) >> 16;
  return (unsigned short)r;
}
__device__ __forceinline__ float bf2f(unsigned short u) {
  return __uint_as_float(((unsigned)u) << 16);
}

// ---------------- kernel 0: weight prep (transpose + hi/lo bf16 split) ----------------
// Wt layout: hi[n][k] at [0, 256*K), lo[n][k] at [256*K, 512*K).
__global__ __launch_bounds__(256) void wprep_kernel(
    const float* __restrict__ tooW, const float* __restrict__ modW0,
    const float* __restrict__ modW1, const float* __restrict__ hvW0,
    unsigned short* __restrict__ tooWt, unsigned short* __restrict__ modW0t,
    unsigned short* __restrict__ modW1t, unsigned short* __restrict__ hvW0t)
{
  int m = blockIdx.x, tid = threadIdx.x;
  const float* W = (m == 0) ? tooW : (m == 1 ? modW0 : (m == 2 ? modW1 : hvW0));
  unsigned short* Wt = (m == 0) ? tooWt : (m == 1 ? modW0t : (m == 2 ? modW1t : hvW0t));
  int K = (m == 0) ? 128 : 256;
  for (int kb = 0; kb < K / 8; kb++) {
    short8 hv, lv;
#pragma unroll
    for (int i = 0; i < 8; i++) {
      float v = W[(kb * 8 + i) * 256 + tid];    // coalesced across tid
      unsigned short hi = f2bf(v);
      float r = v - bf2f(hi);
      hv[i] = (short)hi;
      lv[i] = (short)f2bf(r);
    }
    *(short8*)&Wt[tid * K + kb * 8] = hv;
    *(short8*)&Wt[256 * K + tid * K + kb * 8] = lv;
  }
}

// ---------------- kernel 1: kv = tokens @ tokvW -> K natural + V transposed, bf16 ----------------
// K layout: kn[b][h][token(256)][dh(64)]   (B-frag for QK^T: 16B contiguous dh)
// V layout: vt[b][h][dh(64)][token(256)]   (B-frag for PV:  16B contiguous token)
__global__ __launch_bounds__(256) void kv_kernel(
    const float* __restrict__ tokens, const float* __restrict__ tokvW,
    unsigned short* __restrict__ kn_ws, unsigned short* __restrict__ vt_ws)
{
  __shared__ __align__(16) float tok[256];
  int b = blockIdx.y, j = blockIdx.x, c = threadIdx.x;
  tok[c] = tokens[(b * kM + j) * 256 + c];
  __syncthreads();
  float acc = 0.f;
  for (int i4 = 0; i4 < 64; i4++) {
    float4 t4 = *(const float4*)&tok[i4 * 4];
    acc += t4.x * tokvW[(i4*4+0)*256 + c] + t4.y * tokvW[(i4*4+1)*256 + c]
         + t4.z * tokvW[(i4*4+2)*256 + c] + t4.w * tokvW[(i4*4+3)*256 + c];
  }
  unsigned short bv = f2bf(acc);
  if (c < 128) {
    int h = c >> 6, dd = c & 63;
    kn_ws[((size_t)(b*2+h)*256 + j) * 64 + dd] = bv;
  } else {
    int c2 = c - 128;
    int h = c2 >> 6, dd = c2 & 63;
    vt_ws[((size_t)(b*2+h)*64 + dd) * 256 + j] = bv;
  }
}

// ---------------- kernel 2: per-pixel features (shared across batch) ----------------
__global__ __launch_bounds__(256) void feat_kernel(
    const float* __restrict__ coords,
    const float* __restrict__ Bq, const float* __restrict__ Bl0, const float* __restrict__ Bl1,
    const float* __restrict__ qW, const float* __restrict__ qb,
    const float* __restrict__ toqW,
    const float* __restrict__ bwW0, const float* __restrict__ bwb0,
    const float* __restrict__ bwW1, const float* __restrict__ bwb1,
    float* __restrict__ t_ws, unsigned short* __restrict__ qc_ws,
    float* __restrict__ h0_ws, float* __restrict__ h1_ws)
{
  __shared__ __align__(16) float ffs[3][16][64];
  __shared__ __align__(16) float xq_s[16][256];
  int tid = threadIdx.x;
  int px0 = blockIdx.x * 16;

  for (int r = 0; r < 12; r++) {
    int v = r * 256 + tid;
    int mat = v >> 10;
    int p = (v >> 6) & 15;
    int f = v & 63;
    int fr = f & 31;
    const float* Bm = (mat == 0) ? Bq : (mat == 1 ? Bl0 : Bl1);
    float x = coords[(px0 + p) * 2 + 0];
    float y = coords[(px0 + p) * 2 + 1];
    float proj = 6.283185307179586f * (x * Bm[fr*2+0] + y * Bm[fr*2+1]);
    float s, cc;
    __sincosf(proj, &s, &cc);
    ffs[mat][p][f] = (f < 32) ? cc : s;
  }
  if (tid < 16) {
    float x = coords[(px0 + tid) * 2 + 0];
    float y = coords[(px0 + tid) * 2 + 1];
    int row = min(max((int)(x * 16.0f), 0), 15);
    int col = min(max((int)(y * 16.0f), 0), 15);
    t_ws[px0 + tid] = (float)(row * 16 + col) * (1.0f / 256.0f);
  }
  __syncthreads();

  int c = tid;
  for (int mat = 0; mat < 3; mat++) {
    const float* W = (mat == 0) ? qW : (mat == 1 ? bwW0 : bwW1);
    float acc[16];
#pragma unroll
    for (int p = 0; p < 16; p++) acc[p] = 0.f;
    for (int i4 = 0; i4 < 16; i4++) {
      float w0 = W[(i4*4+0)*256 + c], w1 = W[(i4*4+1)*256 + c];
      float w2 = W[(i4*4+2)*256 + c], w3 = W[(i4*4+3)*256 + c];
#pragma unroll
      for (int p = 0; p < 16; p++) {
        float4 a = *(const float4*)&ffs[mat][p][i4*4];
        acc[p] += a.x*w0 + a.y*w1 + a.z*w2 + a.w*w3;
      }
    }
    if (mat == 0) {
      float bb = qb[c];
#pragma unroll
      for (int p = 0; p < 16; p++) xq_s[p][c] = fmaxf(acc[p] + bb, 0.f);
    } else if (mat == 1) {
      float bb = bwb0[c];
#pragma unroll
      for (int p = 0; p < 16; p++) h0_ws[(px0+p)*256 + c] = fmaxf(acc[p] + bb, 0.f);
    } else {
      float bb = bwb1[c];
#pragma unroll
      for (int p = 0; p < 16; p++) h1_ws[(px0+p)*256 + c] = fmaxf(acc[p] + bb, 0.f);
    }
  }
  __syncthreads();

  {
    int d = tid & 127;
    int half = tid >> 7;
    float acc[8];
#pragma unroll
    for (int p = 0; p < 8; p++) acc[p] = 0.f;
    for (int i4 = 0; i4 < 64; i4++) {
      float w0 = toqW[(i4*4+0)*128 + d], w1 = toqW[(i4*4+1)*128 + d];
      float w2 = toqW[(i4*4+2)*128 + d], w3 = toqW[(i4*4+3)*128 + d];
#pragma unroll
      for (int p = 0; p < 8; p++) {
        float4 a = *(const float4*)&xq_s[half*8 + p][i4*4];
        acc[p] += a.x*w0 + a.y*w1 + a.z*w2 + a.w*w3;
      }
    }
#pragma unroll
    for (int p = 0; p < 8; p++)
      qc_ws[(px0 + half*8 + p) * 128 + d] = f2bf(acc[p]);
  }
}

// ---------------- kernel 3: MFMA cross attention with spatial bias ----------------
// Block: 32 pixels x 1 batch, 4 waves. Per head:
//   QK^T: M=32 (2 mt), N=256 tokens (wave w owns tokens [w*64,w*64+64), 4 nt), K=64 (2 ks).
//   softmax: bias on fp32 acc; row max/sum = per-lane over nt -> shfl butterfly over c -> LDS over waves.
//   P -> LDS (bf16, pitch 264) = C-layout -> A-layout transform.
//   PV: M=32, N=64 dh (wave w owns dh [w*16,w*16+16)), K=256 (8 kt).
// C layout (m89-verified): col = lane&15, row = (lane>>4)*4 + reg.
constexpr int kPPitch = 264;

__global__ __launch_bounds__(256, 2) void attn_kernel(
    const unsigned short* __restrict__ kn_ws,
    const unsigned short* __restrict__ vt_ws,
    const unsigned short* __restrict__ qc_ws,
    const float* __restrict__ t_ws,
    unsigned short* __restrict__ o_bf)
{
  __shared__ __align__(16) unsigned short P_s[32 * kPPitch];
  __shared__ float t_s[32];
  __shared__ float red_max[32][4];
  __shared__ float red_sum[32][4];

  int b = blockIdx.y;
  int px0 = blockIdx.x * 32;
  int tid = threadIdx.x;
  int w = tid >> 6, ln = tid & 63;
  int c = ln & 15, q = ln >> 4;

  if (tid < 32) t_s[tid] = t_ws[px0 + tid];

  const f32x4 zero4 = {0.f, 0.f, 0.f, 0.f};

  for (int h = 0; h < 2; h++) {
    __syncthreads();   // t_s ready (h=0); P_s/red reads of previous head done (h=1)

    // ---- QK^T ----
    f32x4 acc[8];
#pragma unroll
    for (int i = 0; i < 8; i++) acc[i] = zero4;
    const unsigned short* kbase = kn_ws + (size_t)(b*2+h) * 256 * 64;
#pragma unroll
    for (int ks = 0; ks < 2; ks++) {
      int koff = ks * 32 + q * 8;
      short8 a0 = *(const short8*)(qc_ws + (size_t)(px0 + c) * 128 + h*64 + koff);
      short8 a1 = *(const short8*)(qc_ws + (size_t)(px0 + 16 + c) * 128 + h*64 + koff);
#pragma unroll
      for (int nt = 0; nt < 4; nt++) {
        short8 bf = *(const short8*)(kbase + (size_t)(w*64 + nt*16 + c) * 64 + koff);
        acc[0*4+nt] = __builtin_amdgcn_mfma_f32_16x16x32_bf16(a0, bf, acc[0*4+nt], 0, 0, 0);
        acc[1*4+nt] = __builtin_amdgcn_mfma_f32_16x16x32_bf16(a1, bf, acc[1*4+nt], 0, 0, 0);
      }
    }

    // ---- bias + scale (in place), per-lane row max over nt ----
    float lm[2][4];
#pragma unroll
    for (int mt = 0; mt < 2; mt++)
#pragma unroll
      for (int rg = 0; rg < 4; rg++) {
        int row = mt*16 + q*4 + rg;
        float tv = t_s[row];
        float mx = -1e30f;
#pragma unroll
        for (int nt = 0; nt < 4; nt++) {
          int token = w*64 + nt*16 + c;
          float pos = ((float)token + 0.5f) * (1.0f / 256.0f);
          float db = tv - pos;
          float sb = acc[mt*4+nt][rg] * 0.125f - 10.0f * db * db;
          acc[mt*4+nt][rg] = sb;
          mx = fmaxf(mx, sb);
        }
        lm[mt][rg] = mx;
      }
#pragma unroll
    for (int s = 1; s < 16; s <<= 1)
#pragma unroll
      for (int mt = 0; mt < 2; mt++)
#pragma unroll
        for (int rg = 0; rg < 4; rg++)
          lm[mt][rg] = fmaxf(lm[mt][rg], __shfl_xor(lm[mt][rg], s, 64));
    if (c == 0) {
#pragma unroll
      for (int mt = 0; mt < 2; mt++)
#pragma unroll
        for (int rg = 0; rg < 4; rg++)
          red_max[mt*16 + q*4 + rg][w] = lm[mt][rg];
    }
    __syncthreads();

    // ---- exp, P_s write, partial row sums ----
    float ps[2][4];
#pragma unroll
    for (int mt = 0; mt < 2; mt++)
#pragma unroll
      for (int rg = 0; rg < 4; rg++) {
        int row = mt*16 + q*4 + rg;
        float gm = fmaxf(fmaxf(red_max[row][0], red_max[row][1]),
                         fmaxf(red_max[row][2], red_max[row][3]));
        float sum = 0.f;
#pragma unroll
        for (int nt = 0; nt < 4; nt++) {
          float e = __expf(acc[mt*4+nt][rg] - gm);
          sum += e;
          P_s[row * kPPitch + w*64 + nt*16 + c] = f2bf(e);
        }
        ps[mt][rg] = sum;
      }
#pragma unroll
    for (int s = 1; s < 16; s <<= 1)
#pragma unroll
      for (int mt = 0; mt < 2; mt++)
#pragma unroll
        for (int rg = 0; rg < 4; rg++)
          ps[mt][rg] += __shfl_xor(ps[mt][rg], s, 64);
    if (c == 0) {
#pragma unroll
      for (int mt = 0; mt < 2; mt++)
#pragma unroll
        for (int rg = 0; rg < 4; rg++)
          red_sum[mt*16 + q*4 + rg][w] = ps[mt][rg];
    }
    __syncthreads();   // P_s complete + red_sum ready

    // ---- PV: wave w -> dh cols [w*16, w*16+16) ----
    f32x4 oacc[2] = {zero4, zero4};
    const unsigned short* vbase = vt_ws + (size_t)(b*2+h) * 64 * 256;
#pragma unroll
    for (int kt = 0; kt < 8; kt++) {
      int koff = kt * 32 + q * 8;
      short8 bf = *(const short8*)(vbase + (size_t)(w*16 + c) * 256 + koff);
      short8 a0 = *(const short8*)(P_s + (0*16 + c) * kPPitch + koff);
      short8 a1 = *(const short8*)(P_s + (1*16 + c) * kPPitch + koff);
      oacc[0] = __builtin_amdgcn_mfma_f32_16x16x32_bf16(a0, bf, oacc[0], 0, 0, 0);
      oacc[1] = __builtin_amdgcn_mfma_f32_16x16x32_bf16(a1, bf, oacc[1], 0, 0, 0);
    }
#pragma unroll
    for (int mt = 0; mt < 2; mt++)
#pragma unroll
      for (int rg = 0; rg < 4; rg++) {
        int row = mt*16 + q*4 + rg;
        float rinv = 1.0f / (red_sum[row][0] + red_sum[row][1] +
                             red_sum[row][2] + red_sum[row][3]);
        o_bf[((size_t)(b * kHW + px0 + row)) * 128 + h*64 + w*16 + c] =
            f2bf(oacc[mt][rg] * rinv);
      }
  }
}

// ---------------- kernel 4: MFMA MLP chain (hi/lo split weights, fp32 carries) ----------------
constexpr int kPitch  = 264;   // bf16 LDS pitch
constexpr int kHPitch = 260;   // fp32 LDS pitch for h-tiles (16B-aligned rows)

template <int KD>
__device__ __forceinline__ void gemm_block(
    const unsigned short* abuf, const unsigned short* wt,
    f32x4* acc /*[2*4]*/, int r, int q)
{
#pragma unroll
  for (int ks = 0; ks < KD / 32; ks++) {
    int koff = ks * 32 + q * 8;
    short8 bh[4], bl[4];
#pragma unroll
    for (int nt = 0; nt < 4; nt++) {
      bh[nt] = *(const short8*)(wt + (nt * 16 + r) * KD + koff);
      bl[nt] = *(const short8*)(wt + 256 * KD + (nt * 16 + r) * KD + koff);
    }
#pragma unroll
    for (int mt = 0; mt < 2; mt++) {
      short8 a = *(const short8*)(abuf + (mt * 16 + r) * kPitch + koff);
#pragma unroll
      for (int nt = 0; nt < 4; nt++) {
        acc[mt * 4 + nt] = __builtin_amdgcn_mfma_f32_16x16x32_bf16(a, bh[nt], acc[mt * 4 + nt], 0, 0, 0);
        acc[mt * 4 + nt] = __builtin_amdgcn_mfma_f32_16x16x32_bf16(a, bl[nt], acc[mt * 4 + nt], 0, 0, 0);
      }
    }
  }
}

__global__ __launch_bounds__(256, 2) void mlp_kernel(
    const unsigned short* __restrict__ o_bf,
    const float* __restrict__ h0_ws, const float* __restrict__ h1_ws,
    const unsigned short* __restrict__ tooWt, const float* __restrict__ toob,
    const unsigned short* __restrict__ modW0t, const float* __restrict__ modb0,
    const unsigned short* __restrict__ modW1t, const float* __restrict__ modb1,
    const unsigned short* __restrict__ hvW0t, const float* __restrict__ hvb0,
    const float* __restrict__ outW0, const float* __restrict__ outb0,
    const float* __restrict__ outW1, const float* __restrict__ outb1,
    float* __restrict__ dout)
{
  __shared__ __align__(16) unsigned short buf0[32 * kPitch];  // o, then m0
  __shared__ __align__(16) unsigned short buf1[32 * kPitch];  // mod, then S
  __shared__ __align__(16) float hbuf[8 * kHPitch];           // h0 (fp32), then h1
  __shared__ __align__(16) float scratch[32 * 3 * 4];         // out partials [row][k][wave]

  int tid = threadIdx.x;
  int px0 = blockIdx.x * 8;
  int w = tid >> 6, ln = tid & 63;
  int c = ln & 15, q = ln >> 4;

  // ---- stage o (bf16) and h0 (fp32) ----
#pragma unroll
  for (int i = 0; i < 2; i++) {
    int idx = i * 256 + tid;              // 512 x uint4 (8 bf16)
    int r = idx >> 4, c8 = (idx & 15) * 8;
    int b = r >> 3, px = px0 + (r & 7);
    uint4 v = *(const uint4*)(o_bf + ((size_t)(b * kHW + px)) * 128 + c8);
    *(uint4*)&buf0[r * kPitch + c8] = v;
  }
#pragma unroll
  for (int i = 0; i < 2; i++) {
    int idx = i * 256 + tid;              // 512 x float4
    int p = idx >> 6, c4 = (idx & 63) * 4;
    float4 v = *(const float4*)(h0_ws + ((size_t)(px0 + p)) * 256 + c4);
    *(float4*)&hbuf[p * kHPitch + c4] = v;
  }
  __syncthreads();

  f32x4 acc[8];
  const f32x4 zero4 = {0.f, 0.f, 0.f, 0.f};

  // ---- P1: mod = o @ tooW + toob -> buf1 (bf16) ----
#pragma unroll
  for (int i = 0; i < 8; i++) acc[i] = zero4;
  gemm_block<128>(buf0, tooWt + (size_t)w * 64 * 128, acc, c, q);
  __syncthreads();                         // all buf0 (o) reads done
  {
    float bias[4];
#pragma unroll
    for (int nt = 0; nt < 4; nt++) bias[nt] = toob[w * 64 + nt * 16 + c];
#pragma unroll
    for (int mt = 0; mt < 2; mt++)
#pragma unroll
      for (int nt = 0; nt < 4; nt++)
#pragma unroll
        for (int rg = 0; rg < 4; rg++) {
          int row = mt * 16 + q * 4 + rg, col = w * 64 + nt * 16 + c;
          buf1[row * kPitch + col] = f2bf(acc[mt * 4 + nt][rg] + bias[nt]);
        }
  }
  __syncthreads();                         // buf1 (mod) ready

  // ---- P2: m0 = relu(h0 + mod @ modW0 + b) -> fp32 regs ----
  float m0f[8][4];
#pragma unroll
  for (int i = 0; i < 8; i++) acc[i] = zero4;
  gemm_block<256>(buf1, modW0t + (size_t)w * 64 * 256, acc, c, q);
  {
    float bias[4];
#pragma unroll
    for (int nt = 0; nt < 4; nt++) bias[nt] = modb0[w * 64 + nt * 16 + c];
#pragma unroll
    for (int nt = 0; nt < 4; nt++)
#pragma unroll
      for (int rg = 0; rg < 4; rg++) {
        int col = w * 64 + nt * 16 + c;
        float hv = hbuf[((q * 4 + rg) & 7) * kHPitch + col];
#pragma unroll
        for (int mt = 0; mt < 2; mt++)
          m0f[mt * 4 + nt][rg] = fmaxf(acc[mt * 4 + nt][rg] + bias[nt] + hv, 0.f);
      }
  }
  __syncthreads();                         // hbuf (h0) consumed

  // ---- P3: stage h1; m1 = relu(h1 + mod @ modW1 + b); S = m0 + m1 -> buf1 (bf16) ----
#pragma unroll
  for (int i = 0; i < 2; i++) {
    int idx = i * 256 + tid;
    int p = idx >> 6, c4 = (idx & 63) * 4;
    float4 v = *(const float4*)(h1_ws + ((size_t)(px0 + p)) * 256 + c4);
    *(float4*)&hbuf[p * kHPitch + c4] = v;
  }
#pragma unroll
  for (int i = 0; i < 8; i++) acc[i] = zero4;
  gemm_block<256>(buf1, modW1t + (size_t)w * 64 * 256, acc, c, q);
  __syncthreads();                         // h1 staged AND all mod reads done
  {
    float bias[4];
#pragma unroll
    for (int nt = 0; nt < 4; nt++) bias[nt] = modb1[w * 64 + nt * 16 + c];
#pragma unroll
    for (int nt = 0; nt < 4; nt++)
#pragma unroll
      for (int rg = 0; rg < 4; rg++) {
        int col = w * 64 + nt * 16 + c;
        float hv = hbuf[((q * 4 + rg) & 7) * kHPitch + col];
#pragma unroll
        for (int mt = 0; mt < 2; mt++) {
          int row = mt * 16 + q * 4 + rg;
          float v = m0f[mt * 4 + nt][rg] + fmaxf(acc[mt * 4 + nt][rg] + bias[nt] + hv, 0.f);
          buf1[row * kPitch + col] = f2bf(v);
        }
      }
  }
  __syncthreads();                         // buf1 = S

  // ---- P4: hv1 = relu(S @ hvW0 + b) -> fp32 regs only ----
#pragma unroll
  for (int i = 0; i < 8; i++) acc[i] = zero4;
  gemm_block<256>(buf1, hvW0t + (size_t)w * 64 * 256, acc, c, q);
  float hv1f[8][4];
  {
    float bias[4];
#pragma unroll
    for (int nt = 0; nt < 4; nt++) bias[nt] = hvb0[w * 64 + nt * 16 + c];
#pragma unroll
    for (int i = 0; i < 8; i++)
#pragma unroll
      for (int rg = 0; rg < 4; rg++)
        hv1f[i][rg] = fmaxf(acc[i][rg] + bias[i & 3], 0.f);
  }

  // ---- P5: out = hv0 @ outW0 + hv1 @ outW1 + b, full fp32 ----
  {
    float w0v[4][3], w1v[4][3];
#pragma unroll
    for (int nt = 0; nt < 4; nt++) {
      int col = w * 64 + nt * 16 + c;
#pragma unroll
      for (int k = 0; k < 3; k++) {
        w0v[nt][k] = outW0[col * 3 + k];
        w1v[nt][k] = outW1[col * 3 + k];
      }
    }
#pragma unroll
    for (int mt = 0; mt < 2; mt++)
#pragma unroll
      for (int rg = 0; rg < 4; rg++) {
        float pk[3] = {0.f, 0.f, 0.f};
#pragma unroll
        for (int nt = 0; nt < 4; nt++)
#pragma unroll
          for (int k = 0; k < 3; k++)
            pk[k] += m0f[mt * 4 + nt][rg] * w0v[nt][k]
                   + hv1f[mt * 4 + nt][rg] * w1v[nt][k];
#pragma unroll
        for (int k = 0; k < 3; k++) {
#pragma unroll
          for (int s = 1; s < 16; s <<= 1) pk[k] += __shfl_xor(pk[k], s, 64);
        }
        if (c == 0) {
          int row = mt * 16 + q * 4 + rg;
#pragma unroll
          for (int k = 0; k < 3; k++) scratch[(row * 3 + k) * 4 + w] = pk[k];
        }
      }
  }
  __syncthreads();

  if (tid < 96) {
    int row = tid / 3, k = tid % 3;
    int b = row >> 3, px = px0 + (row & 7);
    float s = outb0[k] + outb1[k];
#pragma unroll
    for (int ww = 0; ww < 4; ww++) s += scratch[(row * 3 + k) * 4 + ww];
    dout[((size_t)b * kHW + px) * 3 + k] = s;
  }
}

// ---------------- launch ----------------
extern "C" void kernel_launch(void* const* d_in, const int* in_sizes, int n_in,
                              void* d_out, int out_size, void* d_ws, size_t ws_size,
                              hipStream_t stream) {
  const float* coords = (const float*)d_in[0];
  const float* tokens = (const float*)d_in[1];
  const float* Bq     = (const float*)d_in[2];
  const float* Bl0    = (const float*)d_in[3];
  const float* Bl1    = (const float*)d_in[4];
  const float* qW     = (const float*)d_in[5];
  const float* qb     = (const float*)d_in[6];
  const float* toqW   = (const float*)d_in[7];
  const float* tokvW  = (const float*)d_in[8];
  const float* tooW   = (const float*)d_in[9];
  const float* toob   = (const float*)d_in[10];
  const float* bwW0   = (const float*)d_in[11];
  const float* bwb0   = (const float*)d_in[12];
  const float* bwW1   = (const float*)d_in[13];
  const float* bwb1   = (const float*)d_in[14];
  const float* modW0  = (const float*)d_in[15];
  const float* modb0  = (const float*)d_in[16];
  const float* modW1  = (const float*)d_in[17];
  const float* modb1  = (const float*)d_in[18];
  const float* hvW0   = (const float*)d_in[19];
  const float* hvb0   = (const float*)d_in[20];
  const float* outW0  = (const float*)d_in[21];
  const float* outb0  = (const float*)d_in[22];
  const float* outW1  = (const float*)d_in[23];
  const float* outb1  = (const float*)d_in[24];

  char* ws = (char*)d_ws;
  float*          t_ws   = (float*)(ws + 0);                  //   64 KB
  unsigned short* qc_ws  = (unsigned short*)(ws + 65536);     //    4 MB
  float*          h0_ws  = (float*)(ws + 4259840);            //   16 MB
  float*          h1_ws  = (float*)(ws + 21037056);           //   16 MB
  unsigned short* o_bf   = (unsigned short*)(ws + 37814272);  //   16 MB
  unsigned short* kn_ws  = (unsigned short*)(ws + 54591488);  //  256 KB
  unsigned short* vt_ws  = (unsigned short*)(ws + 54853632);  //  256 KB
  unsigned short* tooWt  = (unsigned short*)(ws + 55115776);  //  128 KB (hi+lo)
  unsigned short* modW0t = (unsigned short*)(ws + 55246848);  //  256 KB
  unsigned short* modW1t = (unsigned short*)(ws + 55508992);  //  256 KB
  unsigned short* hvW0t  = (unsigned short*)(ws + 55771136);  //  256 KB

  wprep_kernel<<<dim3(4), 256, 0, stream>>>(
      tooW, modW0, modW1, hvW0, tooWt, modW0t, modW1t, hvW0t);
  feat_kernel<<<dim3(kHW / 16), 256, 0, stream>>>(
      coords, Bq, Bl0, Bl1, qW, qb, toqW, bwW0, bwb0, bwW1, bwb1,
      t_ws, qc_ws, h0_ws, h1_ws);
  kv_kernel<<<dim3(kM, kB), 256, 0, stream>>>(tokens, tokvW, kn_ws, vt_ws);
  attn_kernel<<<dim3(kHW / 32, kB), 256, 0, stream>>>(kn_ws, vt_ws, qc_ws, t_ws, o_bf);
  mlp_kernel<<<dim3(kHW / 8), 256, 0, stream>>>(
      o_bf, h0_ws, h1_ws, tooWt, toob, modW0t, modb0, modW1t, modb1,
      hvW0t, hvb0, outW0, outb0, outW1, outb1, (float*)d_out);
}

// Round 5
// 306.014 us; speedup vs baseline: 3.4605x; 1.4674x over previous
//
#include <hip/hip_runtime.h>
#include <stdint.h>

constexpr int kHW = 16384;   // 128*128 pixels (grid shared across batch)
constexpr int kB  = 4;
constexpr int kM  = 256;     // tokens

typedef _Float16 half8 __attribute__((ext_vector_type(8)));  // 8 fp16 (4 VGPRs)
typedef __attribute__((ext_vector_type(4))) float f32x4;     // MFMA accum

// ---------------- helpers ----------------
__device__ __forceinline__ unsigned short f2h(float f) {
  _Float16 h = (_Float16)f;
  return __builtin_bit_cast(unsigned short, h);
}
__device__ __forceinline__ float h2f(unsigned short u) {
  return (float)__builtin_bit_cast(_Float16, u);
}

// ---------------- kernel 0: weight prep (transpose + fp16) ----------------
// Wt[n][k] = fp16(W[k][n])  (row-major n, k contiguous -> 16B/lane B-frag loads)
__global__ __launch_bounds__(256) void wprep_kernel(
    const float* __restrict__ tooW, const float* __restrict__ modW0,
    const float* __restrict__ modW1, const float* __restrict__ hvW0,
    unsigned short* __restrict__ tooWt, unsigned short* __restrict__ modW0t,
    unsigned short* __restrict__ modW1t, unsigned short* __restrict__ hvW0t)
{
  int m = blockIdx.x, tid = threadIdx.x;
  const float* W = (m == 0) ? tooW : (m == 1 ? modW0 : (m == 2 ? modW1 : hvW0));
  unsigned short* Wt = (m == 0) ? tooWt : (m == 1 ? modW0t : (m == 2 ? modW1t : hvW0t));
  int K = (m == 0) ? 128 : 256;
  for (int kb = 0; kb < K / 8; kb++) {
    unsigned short sv[8];
#pragma unroll
    for (int i = 0; i < 8; i++)
      sv[i] = f2h(W[(kb * 8 + i) * 256 + tid]);   // coalesced across tid
    *(uint4*)&Wt[tid * K + kb * 8] = *(const uint4*)sv;
  }
}

// ---------------- kernel 1: kv = tokens @ tokvW -> K natural + V transposed, fp16 ----------------
// K layout: kn[b][h][token(256)][dh(64)]   (B-frag for QK^T)
// V layout: vt[b][h][dh(64)][token(256)]   (B-frag for PV)
__global__ __launch_bounds__(256) void kv_kernel(
    const float* __restrict__ tokens, const float* __restrict__ tokvW,
    unsigned short* __restrict__ kn_ws, unsigned short* __restrict__ vt_ws)
{
  __shared__ __align__(16) float tok[256];
  int b = blockIdx.y, j = blockIdx.x, c = threadIdx.x;
  tok[c] = tokens[(b * kM + j) * 256 + c];
  __syncthreads();
  float acc = 0.f;
  for (int i4 = 0; i4 < 64; i4++) {
    float4 t4 = *(const float4*)&tok[i4 * 4];
    acc += t4.x * tokvW[(i4*4+0)*256 + c] + t4.y * tokvW[(i4*4+1)*256 + c]
         + t4.z * tokvW[(i4*4+2)*256 + c] + t4.w * tokvW[(i4*4+3)*256 + c];
  }
  unsigned short hv = f2h(acc);
  if (c < 128) {
    int h = c >> 6, dd = c & 63;
    kn_ws[((size_t)(b*2+h)*256 + j) * 64 + dd] = hv;
  } else {
    int c2 = c - 128;
    int h = c2 >> 6, dd = c2 & 63;
    vt_ws[((size_t)(b*2+h)*64 + dd) * 256 + j] = hv;
  }
}

// ---------------- kernel 2: per-pixel features (shared across batch) ----------------
// h0/h1 and q written fp16.
__global__ __launch_bounds__(256) void feat_kernel(
    const float* __restrict__ coords,
    const float* __restrict__ Bq, const float* __restrict__ Bl0, const float* __restrict__ Bl1,
    const float* __restrict__ qW, const float* __restrict__ qb,
    const float* __restrict__ toqW,
    const float* __restrict__ bwW0, const float* __restrict__ bwb0,
    const float* __restrict__ bwW1, const float* __restrict__ bwb1,
    float* __restrict__ t_ws, unsigned short* __restrict__ qc_ws,
    unsigned short* __restrict__ h0_hf, unsigned short* __restrict__ h1_hf)
{
  __shared__ __align__(16) float ffs[3][16][64];
  __shared__ __align__(16) float xq_s[16][256];
  int tid = threadIdx.x;
  int px0 = blockIdx.x * 16;

  for (int r = 0; r < 12; r++) {
    int v = r * 256 + tid;
    int mat = v >> 10;
    int p = (v >> 6) & 15;
    int f = v & 63;
    int fr = f & 31;
    const float* Bm = (mat == 0) ? Bq : (mat == 1 ? Bl0 : Bl1);
    float x = coords[(px0 + p) * 2 + 0];
    float y = coords[(px0 + p) * 2 + 1];
    float proj = 6.283185307179586f * (x * Bm[fr*2+0] + y * Bm[fr*2+1]);
    float s, cc;
    __sincosf(proj, &s, &cc);
    ffs[mat][p][f] = (f < 32) ? cc : s;
  }
  if (tid < 16) {
    float x = coords[(px0 + tid) * 2 + 0];
    float y = coords[(px0 + tid) * 2 + 1];
    int row = min(max((int)(x * 16.0f), 0), 15);
    int col = min(max((int)(y * 16.0f), 0), 15);
    t_ws[px0 + tid] = (float)(row * 16 + col) * (1.0f / 256.0f);
  }
  __syncthreads();

  int c = tid;
  for (int mat = 0; mat < 3; mat++) {
    const float* W = (mat == 0) ? qW : (mat == 1 ? bwW0 : bwW1);
    float acc[16];
#pragma unroll
    for (int p = 0; p < 16; p++) acc[p] = 0.f;
    for (int i4 = 0; i4 < 16; i4++) {
      float w0 = W[(i4*4+0)*256 + c], w1 = W[(i4*4+1)*256 + c];
      float w2 = W[(i4*4+2)*256 + c], w3 = W[(i4*4+3)*256 + c];
#pragma unroll
      for (int p = 0; p < 16; p++) {
        float4 a = *(const float4*)&ffs[mat][p][i4*4];
        acc[p] += a.x*w0 + a.y*w1 + a.z*w2 + a.w*w3;
      }
    }
    if (mat == 0) {
      float bb = qb[c];
#pragma unroll
      for (int p = 0; p < 16; p++) xq_s[p][c] = fmaxf(acc[p] + bb, 0.f);
    } else if (mat == 1) {
      float bb = bwb0[c];
#pragma unroll
      for (int p = 0; p < 16; p++) h0_hf[(px0+p)*256 + c] = f2h(fmaxf(acc[p] + bb, 0.f));
    } else {
      float bb = bwb1[c];
#pragma unroll
      for (int p = 0; p < 16; p++) h1_hf[(px0+p)*256 + c] = f2h(fmaxf(acc[p] + bb, 0.f));
    }
  }
  __syncthreads();

  {
    int d = tid & 127;
    int half = tid >> 7;
    float acc[8];
#pragma unroll
    for (int p = 0; p < 8; p++) acc[p] = 0.f;
    for (int i4 = 0; i4 < 64; i4++) {
      float w0 = toqW[(i4*4+0)*128 + d], w1 = toqW[(i4*4+1)*128 + d];
      float w2 = toqW[(i4*4+2)*128 + d], w3 = toqW[(i4*4+3)*128 + d];
#pragma unroll
      for (int p = 0; p < 8; p++) {
        float4 a = *(const float4*)&xq_s[half*8 + p][i4*4];
        acc[p] += a.x*w0 + a.y*w1 + a.z*w2 + a.w*w3;
      }
    }
#pragma unroll
    for (int p = 0; p < 8; p++)
      qc_ws[(px0 + half*8 + p) * 128 + d] = f2h(acc[p]);
  }
}

// ---------------- kernel 3: MFMA cross attention with spatial bias (fp16) ----------------
// C layout (m89-verified): col = lane&15, row = (lane>>4)*4 + reg.
constexpr int kPPitch = 264;

__global__ __launch_bounds__(256, 2) void attn_kernel(
    const unsigned short* __restrict__ kn_ws,
    const unsigned short* __restrict__ vt_ws,
    const unsigned short* __restrict__ qc_ws,
    const float* __restrict__ t_ws,
    unsigned short* __restrict__ o_hf)
{
  __shared__ __align__(16) unsigned short P_s[32 * kPPitch];
  __shared__ float t_s[32];
  __shared__ float red_max[32][4];
  __shared__ float red_sum[32][4];

  int b = blockIdx.y;
  int px0 = blockIdx.x * 32;
  int tid = threadIdx.x;
  int w = tid >> 6, ln = tid & 63;
  int c = ln & 15, q = ln >> 4;

  if (tid < 32) t_s[tid] = t_ws[px0 + tid];

  const f32x4 zero4 = {0.f, 0.f, 0.f, 0.f};

  for (int h = 0; h < 2; h++) {
    __syncthreads();

    // ---- QK^T: M=32, N=256 (wave strip of 64), K=64 ----
    f32x4 acc[8];
#pragma unroll
    for (int i = 0; i < 8; i++) acc[i] = zero4;
    const unsigned short* kbase = kn_ws + (size_t)(b*2+h) * 256 * 64;
#pragma unroll
    for (int ks = 0; ks < 2; ks++) {
      int koff = ks * 32 + q * 8;
      half8 a0 = *(const half8*)(qc_ws + (size_t)(px0 + c) * 128 + h*64 + koff);
      half8 a1 = *(const half8*)(qc_ws + (size_t)(px0 + 16 + c) * 128 + h*64 + koff);
#pragma unroll
      for (int nt = 0; nt < 4; nt++) {
        half8 bf = *(const half8*)(kbase + (size_t)(w*64 + nt*16 + c) * 64 + koff);
        acc[0*4+nt] = __builtin_amdgcn_mfma_f32_16x16x32_f16(a0, bf, acc[0*4+nt], 0, 0, 0);
        acc[1*4+nt] = __builtin_amdgcn_mfma_f32_16x16x32_f16(a1, bf, acc[1*4+nt], 0, 0, 0);
      }
    }

    // ---- bias + scale, per-lane row max ----
    float lm[2][4];
#pragma unroll
    for (int mt = 0; mt < 2; mt++)
#pragma unroll
      for (int rg = 0; rg < 4; rg++) {
        int row = mt*16 + q*4 + rg;
        float tv = t_s[row];
        float mx = -1e30f;
#pragma unroll
        for (int nt = 0; nt < 4; nt++) {
          int token = w*64 + nt*16 + c;
          float pos = ((float)token + 0.5f) * (1.0f / 256.0f);
          float db = tv - pos;
          float sb = acc[mt*4+nt][rg] * 0.125f - 10.0f * db * db;
          acc[mt*4+nt][rg] = sb;
          mx = fmaxf(mx, sb);
        }
        lm[mt][rg] = mx;
      }
#pragma unroll
    for (int s = 1; s < 16; s <<= 1)
#pragma unroll
      for (int mt = 0; mt < 2; mt++)
#pragma unroll
        for (int rg = 0; rg < 4; rg++)
          lm[mt][rg] = fmaxf(lm[mt][rg], __shfl_xor(lm[mt][rg], s, 64));
    if (c == 0) {
#pragma unroll
      for (int mt = 0; mt < 2; mt++)
#pragma unroll
        for (int rg = 0; rg < 4; rg++)
          red_max[mt*16 + q*4 + rg][w] = lm[mt][rg];
    }
    __syncthreads();

    // ---- exp, P_s write, partial row sums ----
    float ps[2][4];
#pragma unroll
    for (int mt = 0; mt < 2; mt++)
#pragma unroll
      for (int rg = 0; rg < 4; rg++) {
        int row = mt*16 + q*4 + rg;
        float gm = fmaxf(fmaxf(red_max[row][0], red_max[row][1]),
                         fmaxf(red_max[row][2], red_max[row][3]));
        float sum = 0.f;
#pragma unroll
        for (int nt = 0; nt < 4; nt++) {
          float e = __expf(acc[mt*4+nt][rg] - gm);
          sum += e;
          P_s[row * kPPitch + w*64 + nt*16 + c] = f2h(e);
        }
        ps[mt][rg] = sum;
      }
#pragma unroll
    for (int s = 1; s < 16; s <<= 1)
#pragma unroll
      for (int mt = 0; mt < 2; mt++)
#pragma unroll
        for (int rg = 0; rg < 4; rg++)
          ps[mt][rg] += __shfl_xor(ps[mt][rg], s, 64);
    if (c == 0) {
#pragma unroll
      for (int mt = 0; mt < 2; mt++)
#pragma unroll
        for (int rg = 0; rg < 4; rg++)
          red_sum[mt*16 + q*4 + rg][w] = ps[mt][rg];
    }
    __syncthreads();

    // ---- PV: wave w -> dh cols [w*16, w*16+16), K=256 ----
    f32x4 oacc[2] = {zero4, zero4};
    const unsigned short* vbase = vt_ws + (size_t)(b*2+h) * 64 * 256;
#pragma unroll
    for (int kt = 0; kt < 8; kt++) {
      int koff = kt * 32 + q * 8;
      half8 bf = *(const half8*)(vbase + (size_t)(w*16 + c) * 256 + koff);
      half8 a0 = *(const half8*)(P_s + (0*16 + c) * kPPitch + koff);
      half8 a1 = *(const half8*)(P_s + (1*16 + c) * kPPitch + koff);
      oacc[0] = __builtin_amdgcn_mfma_f32_16x16x32_f16(a0, bf, oacc[0], 0, 0, 0);
      oacc[1] = __builtin_amdgcn_mfma_f32_16x16x32_f16(a1, bf, oacc[1], 0, 0, 0);
    }
#pragma unroll
    for (int mt = 0; mt < 2; mt++)
#pragma unroll
      for (int rg = 0; rg < 4; rg++) {
        int row = mt*16 + q*4 + rg;
        float rinv = 1.0f / (red_sum[row][0] + red_sum[row][1] +
                             red_sum[row][2] + red_sum[row][3]);
        o_hf[((size_t)(b * kHW + px0 + row)) * 128 + h*64 + w*16 + c] =
            f2h(oacc[mt][rg] * rinv);
      }
  }
}

// ---------------- kernel 4: MFMA MLP chain, fp16, M=64 rows (16 px x 4 batch) ----------------
// 4 waves; wave w owns cols [w*64,(w+1)*64). Row = b*16 + px  (b = mt).
// C layout: col = lane&15, row = (lane>>4)*4 + reg.
constexpr int kPitch = 264;   // fp16 LDS pitch

template <int KD>
__device__ __forceinline__ void gemm4(
    const unsigned short* abuf, const unsigned short* wt,
    f32x4* acc /*[4*4]*/, int c, int q)
{
#pragma unroll
  for (int ks = 0; ks < KD / 32; ks++) {
    int koff = ks * 32 + q * 8;
    half8 bfr[4];
#pragma unroll
    for (int nt = 0; nt < 4; nt++)
      bfr[nt] = *(const half8*)(wt + (nt * 16 + c) * KD + koff);
    half8 afr[4];
#pragma unroll
    for (int mt = 0; mt < 4; mt++)
      afr[mt] = *(const half8*)(abuf + (mt * 16 + c) * kPitch + koff);
#pragma unroll
    for (int mt = 0; mt < 4; mt++)
#pragma unroll
      for (int nt = 0; nt < 4; nt++)
        acc[mt * 4 + nt] = __builtin_amdgcn_mfma_f32_16x16x32_f16(afr[mt], bfr[nt], acc[mt * 4 + nt], 0, 0, 0);
  }
}

__global__ __launch_bounds__(256, 2) void mlp_kernel(
    const unsigned short* __restrict__ o_hf,
    const unsigned short* __restrict__ h0_hf, const unsigned short* __restrict__ h1_hf,
    const unsigned short* __restrict__ tooWt, const float* __restrict__ toob,
    const unsigned short* __restrict__ modW0t, const float* __restrict__ modb0,
    const unsigned short* __restrict__ modW1t, const float* __restrict__ modb1,
    const unsigned short* __restrict__ hvW0t, const float* __restrict__ hvb0,
    const float* __restrict__ outW0, const float* __restrict__ outb0,
    const float* __restrict__ outW1, const float* __restrict__ outb1,
    float* __restrict__ dout)
{
  __shared__ __align__(16) unsigned short buf0[64 * kPitch];  // o, then m0 (hv0)
  __shared__ __align__(16) unsigned short buf1[64 * kPitch];  // mod, then S
  __shared__ __align__(16) unsigned short hbuf[16 * kPitch];  // h0, then h1 (per-pixel)
  __shared__ __align__(16) float scratch[64 * 3 * 4];         // out partials [row][k][wave]

  int tid = threadIdx.x;
  int px0 = blockIdx.x * 16;
  int w = tid >> 6, ln = tid & 63;
  int c = ln & 15, q = ln >> 4;

  // ---- stage o (64 rows x 128) and h0 (16 px x 256) ----
#pragma unroll
  for (int i = 0; i < 4; i++) {
    int idx = i * 256 + tid;              // 1024 x uint4 (8 fp16)
    int r = idx >> 4, c8 = (idx & 15) * 8;
    int b = r >> 4, px = r & 15;
    uint4 v = *(const uint4*)(o_hf + ((size_t)(b * kHW + px0 + px)) * 128 + c8);
    *(uint4*)&buf0[r * kPitch + c8] = v;
  }
#pragma unroll
  for (int i = 0; i < 2; i++) {
    int idx = i * 256 + tid;              // 512 x uint4
    int p = idx >> 5, c8 = (idx & 31) * 8;
    uint4 v = *(const uint4*)(h0_hf + ((size_t)(px0 + p)) * 256 + c8);
    *(uint4*)&hbuf[p * kPitch + c8] = v;
  }
  __syncthreads();

  f32x4 acc[16];
  const f32x4 zero4 = {0.f, 0.f, 0.f, 0.f};

  // ---- P1: mod = o @ tooW + toob -> buf1 ----
#pragma unroll
  for (int i = 0; i < 16; i++) acc[i] = zero4;
  gemm4<128>(buf0, tooWt + (size_t)w * 64 * 128, acc, c, q);
  {
    float bias[4];
#pragma unroll
    for (int nt = 0; nt < 4; nt++) bias[nt] = toob[w * 64 + nt * 16 + c];
#pragma unroll
    for (int mt = 0; mt < 4; mt++)
#pragma unroll
      for (int nt = 0; nt < 4; nt++)
#pragma unroll
        for (int rg = 0; rg < 4; rg++) {
          int row = mt * 16 + q * 4 + rg, col = w * 64 + nt * 16 + c;
          buf1[row * kPitch + col] = f2h(acc[mt * 4 + nt][rg] + bias[nt]);
        }
  }
  __syncthreads();   // barrier A: mod ready; all o reads done

  // ---- P2: m0 = relu(h0 + mod @ modW0 + b) -> buf0 ----
#pragma unroll
  for (int i = 0; i < 16; i++) acc[i] = zero4;
  gemm4<256>(buf1, modW0t + (size_t)w * 64 * 256, acc, c, q);
  {
    float bias[4], hr[4][4];
#pragma unroll
    for (int nt = 0; nt < 4; nt++) {
      int col = w * 64 + nt * 16 + c;
      bias[nt] = modb0[col];
#pragma unroll
      for (int rg = 0; rg < 4; rg++)
        hr[nt][rg] = h2f(hbuf[(q * 4 + rg) * kPitch + col]);
    }
#pragma unroll
    for (int mt = 0; mt < 4; mt++)
#pragma unroll
      for (int nt = 0; nt < 4; nt++)
#pragma unroll
        for (int rg = 0; rg < 4; rg++) {
          int row = mt * 16 + q * 4 + rg, col = w * 64 + nt * 16 + c;
          buf0[row * kPitch + col] =
              f2h(fmaxf(acc[mt * 4 + nt][rg] + bias[nt] + hr[nt][rg], 0.f));
        }
  }
  __syncthreads();   // barrier B: h0 consumed, m0 in buf0

  // ---- P3: stage h1; m1 = relu(h1 + mod @ modW1 + b); S = m0 + m1 -> buf1 ----
#pragma unroll
  for (int i = 0; i < 2; i++) {
    int idx = i * 256 + tid;
    int p = idx >> 5, c8 = (idx & 31) * 8;
    uint4 v = *(const uint4*)(h1_hf + ((size_t)(px0 + p)) * 256 + c8);
    *(uint4*)&hbuf[p * kPitch + c8] = v;
  }
#pragma unroll
  for (int i = 0; i < 16; i++) acc[i] = zero4;
  gemm4<256>(buf1, modW1t + (size_t)w * 64 * 256, acc, c, q);
  __syncthreads();   // barrier C: h1 staged AND all mod reads done
  {
    float bias[4], hr[4][4];
#pragma unroll
    for (int nt = 0; nt < 4; nt++) {
      int col = w * 64 + nt * 16 + c;
      bias[nt] = modb1[col];
#pragma unroll
      for (int rg = 0; rg < 4; rg++)
        hr[nt][rg] = h2f(hbuf[(q * 4 + rg) * kPitch + col]);
    }
#pragma unroll
    for (int mt = 0; mt < 4; mt++)
#pragma unroll
      for (int nt = 0; nt < 4; nt++)
#pragma unroll
        for (int rg = 0; rg < 4; rg++) {
          int row = mt * 16 + q * 4 + rg, col = w * 64 + nt * 16 + c;
          float m0v = h2f(buf0[row * kPitch + col]);
          float v = m0v + fmaxf(acc[mt * 4 + nt][rg] + bias[nt] + hr[nt][rg], 0.f);
          buf1[row * kPitch + col] = f2h(v);
        }
  }
  __syncthreads();   // barrier D: S ready

  // ---- P4: hv1 = relu(S @ hvW0 + b); fused out epilogue ----
#pragma unroll
  for (int i = 0; i < 16; i++) acc[i] = zero4;
  gemm4<256>(buf1, hvW0t + (size_t)w * 64 * 256, acc, c, q);
  {
    float bias[4], w0v[4][3], w1v[4][3];
#pragma unroll
    for (int nt = 0; nt < 4; nt++) {
      int col = w * 64 + nt * 16 + c;
      bias[nt] = hvb0[col];
#pragma unroll
      for (int k = 0; k < 3; k++) {
        w0v[nt][k] = outW0[col * 3 + k];
        w1v[nt][k] = outW1[col * 3 + k];
      }
    }
#pragma unroll
    for (int mt = 0; mt < 4; mt++) {
      float pk[4][3];
#pragma unroll
      for (int rg = 0; rg < 4; rg++)
#pragma unroll
        for (int k = 0; k < 3; k++) pk[rg][k] = 0.f;
#pragma unroll
      for (int nt = 0; nt < 4; nt++) {
        int col = w * 64 + nt * 16 + c;
#pragma unroll
        for (int rg = 0; rg < 4; rg++) {
          int row = mt * 16 + q * 4 + rg;
          float hv1 = fmaxf(acc[mt * 4 + nt][rg] + bias[nt], 0.f);
          float m0v = h2f(buf0[row * kPitch + col]);
#pragma unroll
          for (int k = 0; k < 3; k++)
            pk[rg][k] += m0v * w0v[nt][k] + hv1 * w1v[nt][k];
        }
      }
#pragma unroll
      for (int s = 1; s < 16; s <<= 1)
#pragma unroll
        for (int rg = 0; rg < 4; rg++)
#pragma unroll
          for (int k = 0; k < 3; k++)
            pk[rg][k] += __shfl_xor(pk[rg][k], s, 64);
      if (c == 0) {
#pragma unroll
        for (int rg = 0; rg < 4; rg++) {
          int row = mt * 16 + q * 4 + rg;
#pragma unroll
          for (int k = 0; k < 3; k++)
            scratch[row * 12 + k * 4 + w] = pk[rg][k];
        }
      }
    }
  }
  __syncthreads();

  if (tid < 192) {
    int row = tid / 3, k = tid % 3;
    int b = row >> 4, px = px0 + (row & 15);
    float s = outb0[k] + outb1[k];
#pragma unroll
    for (int ww = 0; ww < 4; ww++) s += scratch[row * 12 + k * 4 + ww];
    dout[((size_t)b * kHW + px) * 3 + k] = s;
  }
}

// ---------------- launch ----------------
extern "C" void kernel_launch(void* const* d_in, const int* in_sizes, int n_in,
                              void* d_out, int out_size, void* d_ws, size_t ws_size,
                              hipStream_t stream) {
  const float* coords = (const float*)d_in[0];
  const float* tokens = (const float*)d_in[1];
  const float* Bq     = (const float*)d_in[2];
  const float* Bl0    = (const float*)d_in[3];
  const float* Bl1    = (const float*)d_in[4];
  const float* qW     = (const float*)d_in[5];
  const float* qb     = (const float*)d_in[6];
  const float* toqW   = (const float*)d_in[7];
  const float* tokvW  = (const float*)d_in[8];
  const float* tooW   = (const float*)d_in[9];
  const float* toob   = (const float*)d_in[10];
  const float* bwW0   = (const float*)d_in[11];
  const float* bwb0   = (const float*)d_in[12];
  const float* bwW1   = (const float*)d_in[13];
  const float* bwb1   = (const float*)d_in[14];
  const float* modW0  = (const float*)d_in[15];
  const float* modb0  = (const float*)d_in[16];
  const float* modW1  = (const float*)d_in[17];
  const float* modb1  = (const float*)d_in[18];
  const float* hvW0   = (const float*)d_in[19];
  const float* hvb0   = (const float*)d_in[20];
  const float* outW0  = (const float*)d_in[21];
  const float* outb0  = (const float*)d_in[22];
  const float* outW1  = (const float*)d_in[23];
  const float* outb1  = (const float*)d_in[24];

  char* ws = (char*)d_ws;
  float*          t_ws   = (float*)(ws + 0);                  //   64 KB
  unsigned short* qc_ws  = (unsigned short*)(ws + 65536);     //    4 MB
  unsigned short* h0_hf  = (unsigned short*)(ws + 4259840);   //    8 MB
  unsigned short* h1_hf  = (unsigned short*)(ws + 12648448);  //    8 MB
  unsigned short* o_hf   = (unsigned short*)(ws + 21037056);  //   16 MB
  unsigned short* kn_ws  = (unsigned short*)(ws + 37814272);  //  256 KB
  unsigned short* vt_ws  = (unsigned short*)(ws + 38076416);  //  256 KB
  unsigned short* tooWt  = (unsigned short*)(ws + 38338560);  //   64 KB
  unsigned short* modW0t = (unsigned short*)(ws + 38404096);  //  128 KB
  unsigned short* modW1t = (unsigned short*)(ws + 38535168);  //  128 KB
  unsigned short* hvW0t  = (unsigned short*)(ws + 38666240);  //  128 KB

  wprep_kernel<<<dim3(4), 256, 0, stream>>>(
      tooW, modW0, modW1, hvW0, tooWt, modW0t, modW1t, hvW0t);
  feat_kernel<<<dim3(kHW / 16), 256, 0, stream>>>(
      coords, Bq, Bl0, Bl1, qW, qb, toqW, bwW0, bwb0, bwW1, bwb1,
      t_ws, qc_ws, h0_hf, h1_hf);
  kv_kernel<<<dim3(kM, kB), 256, 0, stream>>>(tokens, tokvW, kn_ws, vt_ws);
  attn_kernel<<<dim3(kHW / 32, kB), 256, 0, stream>>>(kn_ws, vt_ws, qc_ws, t_ws, o_hf);
  mlp_kernel<<<dim3(kHW / 16), 256, 0, stream>>>(
      o_hf, h0_hf, h1_hf, tooWt, toob, modW0t, modb0, modW1t, modb1,
      hvW0t, hvb0, outW0, outb0, outW1, outb1, (float*)d_out);
}

// Round 6
// 257.289 us; speedup vs baseline: 4.1159x; 1.1894x over previous
//
#include <hip/hip_runtime.h>
#include <stdint.h>

constexpr int kHW = 16384;   // 128*128 pixels (grid shared across batch)
constexpr int kB  = 4;
constexpr int kM  = 256;     // tokens

typedef _Float16 half8 __attribute__((ext_vector_type(8)));  // 8 fp16 (4 VGPRs)
typedef __attribute__((ext_vector_type(4))) float f32x4;     // MFMA accum

// ---------------- helpers ----------------
__device__ __forceinline__ unsigned short f2h(float f) {
  _Float16 h = (_Float16)f;
  return __builtin_bit_cast(unsigned short, h);
}
__device__ __forceinline__ float h2f(unsigned short u) {
  return (float)__builtin_bit_cast(_Float16, u);
}

// ---------------- kernel 0: weight prep (transpose + fp16) ----------------
// Wt[n][k] = fp16(W[k][n])  (row-major n, k contiguous -> 16B/lane B-frag loads)
__global__ __launch_bounds__(256) void wprep_kernel(
    const float* __restrict__ tooW, const float* __restrict__ modW0,
    const float* __restrict__ modW1, const float* __restrict__ hvW0,
    const float* __restrict__ qW, const float* __restrict__ bwW0,
    const float* __restrict__ bwW1, const float* __restrict__ toqW,
    unsigned short* __restrict__ tooWt, unsigned short* __restrict__ modW0t,
    unsigned short* __restrict__ modW1t, unsigned short* __restrict__ hvW0t,
    unsigned short* __restrict__ qWt, unsigned short* __restrict__ bw0t,
    unsigned short* __restrict__ bw1t, unsigned short* __restrict__ toqWt)
{
  int m = blockIdx.x, tid = threadIdx.x;
  const float* Ws[8] = {tooW, modW0, modW1, hvW0, qW, bwW0, bwW1, toqW};
  unsigned short* Wts[8] = {tooWt, modW0t, modW1t, hvW0t, qWt, bw0t, bw1t, toqWt};
  const int Ks[8] = {128, 256, 256, 256, 64, 64, 64, 256};
  const int Ns[8] = {256, 256, 256, 256, 256, 256, 256, 128};
  const float* W = Ws[m];
  unsigned short* Wt = Wts[m];
  int K = Ks[m], N = Ns[m];
  if (tid < N) {
    for (int kb = 0; kb < K / 8; kb++) {
      unsigned short sv[8];
#pragma unroll
      for (int i = 0; i < 8; i++)
        sv[i] = f2h(W[(kb * 8 + i) * N + tid]);   // coalesced across tid
      *(uint4*)&Wt[tid * K + kb * 8] = *(const uint4*)sv;
    }
  }
}

// ---------------- kernel 1: kv = tokens @ tokvW -> K natural + V transposed, fp16 ----------------
__global__ __launch_bounds__(256) void kv_kernel(
    const float* __restrict__ tokens, const float* __restrict__ tokvW,
    unsigned short* __restrict__ kn_ws, unsigned short* __restrict__ vt_ws)
{
  __shared__ __align__(16) float tok[256];
  int b = blockIdx.y, j = blockIdx.x, c = threadIdx.x;
  tok[c] = tokens[(b * kM + j) * 256 + c];
  __syncthreads();
  float acc = 0.f;
  for (int i4 = 0; i4 < 64; i4++) {
    float4 t4 = *(const float4*)&tok[i4 * 4];
    acc += t4.x * tokvW[(i4*4+0)*256 + c] + t4.y * tokvW[(i4*4+1)*256 + c]
         + t4.z * tokvW[(i4*4+2)*256 + c] + t4.w * tokvW[(i4*4+3)*256 + c];
  }
  unsigned short hv = f2h(acc);
  if (c < 128) {
    int h = c >> 6, dd = c & 63;
    kn_ws[((size_t)(b*2+h)*256 + j) * 64 + dd] = hv;
  } else {
    int c2 = c - 128;
    int h = c2 >> 6, dd = c2 & 63;
    vt_ws[((size_t)(b*2+h)*64 + dd) * 256 + j] = hv;
  }
}

// ---------------- kernel 2: MFMA per-pixel features (shared across batch) ----------------
// Block: 32 px, 4 waves. ff (fp16 LDS) -> 3 GEMMs K=64 (xq->LDS, h0/h1->global)
// -> q GEMM K=256 -> global. C layout: col = lane&15, row = (lane>>4)*4 + reg.
constexpr int kFPitch = 72;    // fp16 pitch for ff rows (144 B = 9*16)
constexpr int kXPitch = 264;   // fp16 pitch for xq rows

__global__ __launch_bounds__(256, 2) void feat_kernel(
    const float* __restrict__ coords,
    const float* __restrict__ Bq, const float* __restrict__ Bl0, const float* __restrict__ Bl1,
    const float* __restrict__ qb, const float* __restrict__ bwb0, const float* __restrict__ bwb1,
    const unsigned short* __restrict__ qWt, const unsigned short* __restrict__ bw0t,
    const unsigned short* __restrict__ bw1t, const unsigned short* __restrict__ toqWt,
    float* __restrict__ t_ws, unsigned short* __restrict__ qc_ws,
    unsigned short* __restrict__ h0_hf, unsigned short* __restrict__ h1_hf)
{
  __shared__ __align__(16) unsigned short ff_s[3][32][kFPitch];
  __shared__ __align__(16) unsigned short xq_s[32][kXPitch];
  __shared__ float coords_s[64];

  int tid = threadIdx.x;
  int px0 = blockIdx.x * 32;
  int w = tid >> 6, ln = tid & 63;
  int c = ln & 15, q = ln >> 4;

  if (tid < 64) coords_s[tid] = coords[px0 * 2 + tid];
  __syncthreads();

  // ---- Fourier features: 3 mats * 32 px * 64 f = 6144 vals, 24/thread ----
#pragma unroll
  for (int r = 0; r < 24; r++) {
    int v = r * 256 + tid;
    int mat = v >> 11;
    int p = (v >> 6) & 31;
    int f = v & 63;
    int fr = f & 31;
    const float* Bm = (mat == 0) ? Bq : (mat == 1 ? Bl0 : Bl1);
    float x = coords_s[p * 2 + 0];
    float y = coords_s[p * 2 + 1];
    float proj = 6.283185307179586f * (x * Bm[fr*2+0] + y * Bm[fr*2+1]);
    float s, cc;
    __sincosf(proj, &s, &cc);
    ff_s[mat][p][f] = f2h((f < 32) ? cc : s);
  }
  if (tid < 32) {
    float x = coords_s[tid * 2 + 0];
    float y = coords_s[tid * 2 + 1];
    int row = min(max((int)(x * 16.0f), 0), 15);
    int col = min(max((int)(y * 16.0f), 0), 15);
    t_ws[px0 + tid] = (float)(row * 16 + col) * (1.0f / 256.0f);
  }
  __syncthreads();

  const f32x4 zero4 = {0.f, 0.f, 0.f, 0.f};

  // ---- 3 GEMMs: M=32, N=256 (wave owns 64 cols), K=64 ----
  for (int mat = 0; mat < 3; mat++) {
    const unsigned short* Wt = (mat == 0) ? qWt : (mat == 1 ? bw0t : bw1t);
    const float* bias = (mat == 0) ? qb : (mat == 1 ? bwb0 : bwb1);
    f32x4 acc[8];
#pragma unroll
    for (int i = 0; i < 8; i++) acc[i] = zero4;
#pragma unroll
    for (int ks = 0; ks < 2; ks++) {
      int koff = ks * 32 + q * 8;
      half8 bfr[4];
#pragma unroll
      for (int nt = 0; nt < 4; nt++)
        bfr[nt] = *(const half8*)(Wt + (size_t)(w*64 + nt*16 + c) * 64 + koff);
      half8 afr[2];
#pragma unroll
      for (int mt = 0; mt < 2; mt++)
        afr[mt] = *(const half8*)(&ff_s[mat][mt*16 + c][koff]);
#pragma unroll
      for (int mt = 0; mt < 2; mt++)
#pragma unroll
        for (int nt = 0; nt < 4; nt++)
          acc[mt*4+nt] = __builtin_amdgcn_mfma_f32_16x16x32_f16(afr[mt], bfr[nt], acc[mt*4+nt], 0, 0, 0);
    }
    float bv[4];
#pragma unroll
    for (int nt = 0; nt < 4; nt++) bv[nt] = bias[w*64 + nt*16 + c];
#pragma unroll
    for (int mt = 0; mt < 2; mt++)
#pragma unroll
      for (int nt = 0; nt < 4; nt++)
#pragma unroll
        for (int rg = 0; rg < 4; rg++) {
          int row = mt*16 + q*4 + rg, col = w*64 + nt*16 + c;
          unsigned short hv = f2h(fmaxf(acc[mt*4+nt][rg] + bv[nt], 0.f));
          if (mat == 0)      xq_s[row][col] = hv;
          else if (mat == 1) h0_hf[((size_t)(px0 + row)) * 256 + col] = hv;
          else               h1_hf[((size_t)(px0 + row)) * 256 + col] = hv;
        }
  }
  __syncthreads();   // xq_s ready

  // ---- q GEMM: M=32, N=128 (wave owns 32 cols), K=256, no bias ----
  {
    f32x4 acc2[4];
#pragma unroll
    for (int i = 0; i < 4; i++) acc2[i] = zero4;
#pragma unroll
    for (int kt = 0; kt < 8; kt++) {
      int koff = kt * 32 + q * 8;
      half8 bfr[2];
#pragma unroll
      for (int nt = 0; nt < 2; nt++)
        bfr[nt] = *(const half8*)(toqWt + (size_t)(w*32 + nt*16 + c) * 256 + koff);
      half8 afr[2];
#pragma unroll
      for (int mt = 0; mt < 2; mt++)
        afr[mt] = *(const half8*)(&xq_s[mt*16 + c][koff]);
#pragma unroll
      for (int mt = 0; mt < 2; mt++)
#pragma unroll
        for (int nt = 0; nt < 2; nt++)
          acc2[mt*2+nt] = __builtin_amdgcn_mfma_f32_16x16x32_f16(afr[mt], bfr[nt], acc2[mt*2+nt], 0, 0, 0);
    }
#pragma unroll
    for (int mt = 0; mt < 2; mt++)
#pragma unroll
      for (int nt = 0; nt < 2; nt++)
#pragma unroll
        for (int rg = 0; rg < 4; rg++) {
          int row = mt*16 + q*4 + rg, col = w*32 + nt*16 + c;
          qc_ws[((size_t)(px0 + row)) * 128 + col] = f2h(acc2[mt*2+nt][rg]);
        }
  }
}

// ---------------- kernel 3: MFMA cross attention with spatial bias (fp16) ----------------
// C layout (m89-verified): col = lane&15, row = (lane>>4)*4 + reg.
constexpr int kPPitch = 264;

__global__ __launch_bounds__(256, 2) void attn_kernel(
    const unsigned short* __restrict__ kn_ws,
    const unsigned short* __restrict__ vt_ws,
    const unsigned short* __restrict__ qc_ws,
    const float* __restrict__ t_ws,
    unsigned short* __restrict__ o_hf)
{
  __shared__ __align__(16) unsigned short P_s[32 * kPPitch];
  __shared__ float t_s[32];
  __shared__ float red_max[32][4];
  __shared__ float red_sum[32][4];

  int b = blockIdx.y;
  int px0 = blockIdx.x * 32;
  int tid = threadIdx.x;
  int w = tid >> 6, ln = tid & 63;
  int c = ln & 15, q = ln >> 4;

  if (tid < 32) t_s[tid] = t_ws[px0 + tid];

  const f32x4 zero4 = {0.f, 0.f, 0.f, 0.f};

  for (int h = 0; h < 2; h++) {
    __syncthreads();

    // ---- QK^T: M=32, N=256 (wave strip of 64), K=64 ----
    f32x4 acc[8];
#pragma unroll
    for (int i = 0; i < 8; i++) acc[i] = zero4;
    const unsigned short* kbase = kn_ws + (size_t)(b*2+h) * 256 * 64;
#pragma unroll
    for (int ks = 0; ks < 2; ks++) {
      int koff = ks * 32 + q * 8;
      half8 a0 = *(const half8*)(qc_ws + (size_t)(px0 + c) * 128 + h*64 + koff);
      half8 a1 = *(const half8*)(qc_ws + (size_t)(px0 + 16 + c) * 128 + h*64 + koff);
#pragma unroll
      for (int nt = 0; nt < 4; nt++) {
        half8 bf = *(const half8*)(kbase + (size_t)(w*64 + nt*16 + c) * 64 + koff);
        acc[0*4+nt] = __builtin_amdgcn_mfma_f32_16x16x32_f16(a0, bf, acc[0*4+nt], 0, 0, 0);
        acc[1*4+nt] = __builtin_amdgcn_mfma_f32_16x16x32_f16(a1, bf, acc[1*4+nt], 0, 0, 0);
      }
    }

    // ---- bias + scale, per-lane row max ----
    float lm[2][4];
#pragma unroll
    for (int mt = 0; mt < 2; mt++)
#pragma unroll
      for (int rg = 0; rg < 4; rg++) {
        int row = mt*16 + q*4 + rg;
        float tv = t_s[row];
        float mx = -1e30f;
#pragma unroll
        for (int nt = 0; nt < 4; nt++) {
          int token = w*64 + nt*16 + c;
          float pos = ((float)token + 0.5f) * (1.0f / 256.0f);
          float db = tv - pos;
          float sb = acc[mt*4+nt][rg] * 0.125f - 10.0f * db * db;
          acc[mt*4+nt][rg] = sb;
          mx = fmaxf(mx, sb);
        }
        lm[mt][rg] = mx;
      }
#pragma unroll
    for (int s = 1; s < 16; s <<= 1)
#pragma unroll
      for (int mt = 0; mt < 2; mt++)
#pragma unroll
        for (int rg = 0; rg < 4; rg++)
          lm[mt][rg] = fmaxf(lm[mt][rg], __shfl_xor(lm[mt][rg], s, 64));
    if (c == 0) {
#pragma unroll
      for (int mt = 0; mt < 2; mt++)
#pragma unroll
        for (int rg = 0; rg < 4; rg++)
          red_max[mt*16 + q*4 + rg][w] = lm[mt][rg];
    }
    __syncthreads();

    // ---- exp, P_s write, partial row sums ----
    float ps[2][4];
#pragma unroll
    for (int mt = 0; mt < 2; mt++)
#pragma unroll
      for (int rg = 0; rg < 4; rg++) {
        int row = mt*16 + q*4 + rg;
        float gm = fmaxf(fmaxf(red_max[row][0], red_max[row][1]),
                         fmaxf(red_max[row][2], red_max[row][3]));
        float sum = 0.f;
#pragma unroll
        for (int nt = 0; nt < 4; nt++) {
          float e = __expf(acc[mt*4+nt][rg] - gm);
          sum += e;
          P_s[row * kPPitch + w*64 + nt*16 + c] = f2h(e);
        }
        ps[mt][rg] = sum;
      }
#pragma unroll
    for (int s = 1; s < 16; s <<= 1)
#pragma unroll
      for (int mt = 0; mt < 2; mt++)
#pragma unroll
        for (int rg = 0; rg < 4; rg++)
          ps[mt][rg] += __shfl_xor(ps[mt][rg], s, 64);
    if (c == 0) {
#pragma unroll
      for (int mt = 0; mt < 2; mt++)
#pragma unroll
        for (int rg = 0; rg < 4; rg++)
          red_sum[mt*16 + q*4 + rg][w] = ps[mt][rg];
    }
    __syncthreads();

    // ---- PV: wave w -> dh cols [w*16, w*16+16), K=256 ----
    f32x4 oacc[2] = {zero4, zero4};
    const unsigned short* vbase = vt_ws + (size_t)(b*2+h) * 64 * 256;
#pragma unroll
    for (int kt = 0; kt < 8; kt++) {
      int koff = kt * 32 + q * 8;
      half8 bf = *(const half8*)(vbase + (size_t)(w*16 + c) * 256 + koff);
      half8 a0 = *(const half8*)(P_s + (0*16 + c) * kPPitch + koff);
      half8 a1 = *(const half8*)(P_s + (1*16 + c) * kPPitch + koff);
      oacc[0] = __builtin_amdgcn_mfma_f32_16x16x32_f16(a0, bf, oacc[0], 0, 0, 0);
      oacc[1] = __builtin_amdgcn_mfma_f32_16x16x32_f16(a1, bf, oacc[1], 0, 0, 0);
    }
#pragma unroll
    for (int mt = 0; mt < 2; mt++)
#pragma unroll
      for (int rg = 0; rg < 4; rg++) {
        int row = mt*16 + q*4 + rg;
        float rinv = 1.0f / (red_sum[row][0] + red_sum[row][1] +
                             red_sum[row][2] + red_sum[row][3]);
        o_hf[((size_t)(b * kHW + px0 + row)) * 128 + h*64 + w*16 + c] =
            f2h(oacc[mt][rg] * rinv);
      }
  }
}

// ---------------- kernel 4: MFMA MLP chain, fp16, M=64 rows (16 px x 4 batch) ----------------
constexpr int kPitch = 264;   // fp16 LDS pitch

template <int KD>
__device__ __forceinline__ void gemm4(
    const unsigned short* abuf, const unsigned short* wt,
    f32x4* acc /*[4*4]*/, int c, int q)
{
#pragma unroll
  for (int ks = 0; ks < KD / 32; ks++) {
    int koff = ks * 32 + q * 8;
    half8 bfr[4];
#pragma unroll
    for (int nt = 0; nt < 4; nt++)
      bfr[nt] = *(const half8*)(wt + (nt * 16 + c) * KD + koff);
    half8 afr[4];
#pragma unroll
    for (int mt = 0; mt < 4; mt++)
      afr[mt] = *(const half8*)(abuf + (mt * 16 + c) * kPitch + koff);
#pragma unroll
    for (int mt = 0; mt < 4; mt++)
#pragma unroll
      for (int nt = 0; nt < 4; nt++)
        acc[mt * 4 + nt] = __builtin_amdgcn_mfma_f32_16x16x32_f16(afr[mt], bfr[nt], acc[mt * 4 + nt], 0, 0, 0);
  }
}

__global__ __launch_bounds__(256, 2) void mlp_kernel(
    const unsigned short* __restrict__ o_hf,
    const unsigned short* __restrict__ h0_hf, const unsigned short* __restrict__ h1_hf,
    const unsigned short* __restrict__ tooWt, const float* __restrict__ toob,
    const unsigned short* __restrict__ modW0t, const float* __restrict__ modb0,
    const unsigned short* __restrict__ modW1t, const float* __restrict__ modb1,
    const unsigned short* __restrict__ hvW0t, const float* __restrict__ hvb0,
    const float* __restrict__ outW0, const float* __restrict__ outb0,
    const float* __restrict__ outW1, const float* __restrict__ outb1,
    float* __restrict__ dout)
{
  __shared__ __align__(16) unsigned short buf0[64 * kPitch];  // o, then m0 (hv0)
  __shared__ __align__(16) unsigned short buf1[64 * kPitch];  // mod, then S
  __shared__ __align__(16) unsigned short hbuf[16 * kPitch];  // h0, then h1 (per-pixel)
  __shared__ __align__(16) float scratch[64 * 3 * 4];         // out partials [row][k][wave]

  int tid = threadIdx.x;
  int px0 = blockIdx.x * 16;
  int w = tid >> 6, ln = tid & 63;
  int c = ln & 15, q = ln >> 4;

  // ---- stage o (64 rows x 128) and h0 (16 px x 256) ----
#pragma unroll
  for (int i = 0; i < 4; i++) {
    int idx = i * 256 + tid;              // 1024 x uint4 (8 fp16)
    int r = idx >> 4, c8 = (idx & 15) * 8;
    int b = r >> 4, px = r & 15;
    uint4 v = *(const uint4*)(o_hf + ((size_t)(b * kHW + px0 + px)) * 128 + c8);
    *(uint4*)&buf0[r * kPitch + c8] = v;
  }
#pragma unroll
  for (int i = 0; i < 2; i++) {
    int idx = i * 256 + tid;              // 512 x uint4
    int p = idx >> 5, c8 = (idx & 31) * 8;
    uint4 v = *(const uint4*)(h0_hf + ((size_t)(px0 + p)) * 256 + c8);
    *(uint4*)&hbuf[p * kPitch + c8] = v;
  }
  __syncthreads();

  f32x4 acc[16];
  const f32x4 zero4 = {0.f, 0.f, 0.f, 0.f};

  // ---- P1: mod = o @ tooW + toob -> buf1 ----
#pragma unroll
  for (int i = 0; i < 16; i++) acc[i] = zero4;
  gemm4<128>(buf0, tooWt + (size_t)w * 64 * 128, acc, c, q);
  {
    float bias[4];
#pragma unroll
    for (int nt = 0; nt < 4; nt++) bias[nt] = toob[w * 64 + nt * 16 + c];
#pragma unroll
    for (int mt = 0; mt < 4; mt++)
#pragma unroll
      for (int nt = 0; nt < 4; nt++)
#pragma unroll
        for (int rg = 0; rg < 4; rg++) {
          int row = mt * 16 + q * 4 + rg, col = w * 64 + nt * 16 + c;
          buf1[row * kPitch + col] = f2h(acc[mt * 4 + nt][rg] + bias[nt]);
        }
  }
  __syncthreads();   // barrier A: mod ready; all o reads done

  // ---- P2: m0 = relu(h0 + mod @ modW0 + b) -> buf0 ----
#pragma unroll
  for (int i = 0; i < 16; i++) acc[i] = zero4;
  gemm4<256>(buf1, modW0t + (size_t)w * 64 * 256, acc, c, q);
  {
    float bias[4], hr[4][4];
#pragma unroll
    for (int nt = 0; nt < 4; nt++) {
      int col = w * 64 + nt * 16 + c;
      bias[nt] = modb0[col];
#pragma unroll
      for (int rg = 0; rg < 4; rg++)
        hr[nt][rg] = h2f(hbuf[(q * 4 + rg) * kPitch + col]);
    }
#pragma unroll
    for (int mt = 0; mt < 4; mt++)
#pragma unroll
      for (int nt = 0; nt < 4; nt++)
#pragma unroll
        for (int rg = 0; rg < 4; rg++) {
          int row = mt * 16 + q * 4 + rg, col = w * 64 + nt * 16 + c;
          buf0[row * kPitch + col] =
              f2h(fmaxf(acc[mt * 4 + nt][rg] + bias[nt] + hr[nt][rg], 0.f));
        }
  }
  __syncthreads();   // barrier B: h0 consumed, m0 in buf0

  // ---- P3: stage h1; m1 = relu(h1 + mod @ modW1 + b); S = m0 + m1 -> buf1 ----
#pragma unroll
  for (int i = 0; i < 2; i++) {
    int idx = i * 256 + tid;
    int p = idx >> 5, c8 = (idx & 31) * 8;
    uint4 v = *(const uint4*)(h1_hf + ((size_t)(px0 + p)) * 256 + c8);
    *(uint4*)&hbuf[p * kPitch + c8] = v;
  }
#pragma unroll
  for (int i = 0; i < 16; i++) acc[i] = zero4;
  gemm4<256>(buf1, modW1t + (size_t)w * 64 * 256, acc, c, q);
  __syncthreads();   // barrier C: h1 staged AND all mod reads done
  {
    float bias[4], hr[4][4];
#pragma unroll
    for (int nt = 0; nt < 4; nt++) {
      int col = w * 64 + nt * 16 + c;
      bias[nt] = modb1[col];
#pragma unroll
      for (int rg = 0; rg < 4; rg++)
        hr[nt][rg] = h2f(hbuf[(q * 4 + rg) * kPitch + col]);
    }
#pragma unroll
    for (int mt = 0; mt < 4; mt++)
#pragma unroll
      for (int nt = 0; nt < 4; nt++)
#pragma unroll
        for (int rg = 0; rg < 4; rg++) {
          int row = mt * 16 + q * 4 + rg, col = w * 64 + nt * 16 + c;
          float m0v = h2f(buf0[row * kPitch + col]);
          float v = m0v + fmaxf(acc[mt * 4 + nt][rg] + bias[nt] + hr[nt][rg], 0.f);
          buf1[row * kPitch + col] = f2h(v);
        }
  }
  __syncthreads();   // barrier D: S ready

  // ---- P4: hv1 = relu(S @ hvW0 + b); fused out epilogue ----
#pragma unroll
  for (int i = 0; i < 16; i++) acc[i] = zero4;
  gemm4<256>(buf1, hvW0t + (size_t)w * 64 * 256, acc, c, q);
  {
    float bias[4], w0v[4][3], w1v[4][3];
#pragma unroll
    for (int nt = 0; nt < 4; nt++) {
      int col = w * 64 + nt * 16 + c;
      bias[nt] = hvb0[col];
#pragma unroll
      for (int k = 0; k < 3; k++) {
        w0v[nt][k] = outW0[col * 3 + k];
        w1v[nt][k] = outW1[col * 3 + k];
      }
    }
#pragma unroll
    for (int mt = 0; mt < 4; mt++) {
      float pk[4][3];
#pragma unroll
      for (int rg = 0; rg < 4; rg++)
#pragma unroll
        for (int k = 0; k < 3; k++) pk[rg][k] = 0.f;
#pragma unroll
      for (int nt = 0; nt < 4; nt++) {
        int col = w * 64 + nt * 16 + c;
#pragma unroll
        for (int rg = 0; rg < 4; rg++) {
          int row = mt * 16 + q * 4 + rg;
          float hv1 = fmaxf(acc[mt * 4 + nt][rg] + bias[nt], 0.f);
          float m0v = h2f(buf0[row * kPitch + col]);
#pragma unroll
          for (int k = 0; k < 3; k++)
            pk[rg][k] += m0v * w0v[nt][k] + hv1 * w1v[nt][k];
        }
      }
#pragma unroll
      for (int s = 1; s < 16; s <<= 1)
#pragma unroll
        for (int rg = 0; rg < 4; rg++)
#pragma unroll
          for (int k = 0; k < 3; k++)
            pk[rg][k] += __shfl_xor(pk[rg][k], s, 64);
      if (c == 0) {
#pragma unroll
        for (int rg = 0; rg < 4; rg++) {
          int row = mt * 16 + q * 4 + rg;
#pragma unroll
          for (int k = 0; k < 3; k++)
            scratch[row * 12 + k * 4 + w] = pk[rg][k];
        }
      }
    }
  }
  __syncthreads();

  if (tid < 192) {
    int row = tid / 3, k = tid % 3;
    int b = row >> 4, px = px0 + (row & 15);
    float s = outb0[k] + outb1[k];
#pragma unroll
    for (int ww = 0; ww < 4; ww++) s += scratch[row * 12 + k * 4 + ww];
    dout[((size_t)b * kHW + px) * 3 + k] = s;
  }
}

// ---------------- launch ----------------
extern "C" void kernel_launch(void* const* d_in, const int* in_sizes, int n_in,
                              void* d_out, int out_size, void* d_ws, size_t ws_size,
                              hipStream_t stream) {
  const float* coords = (const float*)d_in[0];
  const float* tokens = (const float*)d_in[1];
  const float* Bq     = (const float*)d_in[2];
  const float* Bl0    = (const float*)d_in[3];
  const float* Bl1    = (const float*)d_in[4];
  const float* qW     = (const float*)d_in[5];
  const float* qb     = (const float*)d_in[6];
  const float* toqW   = (const float*)d_in[7];
  const float* tokvW  = (const float*)d_in[8];
  const float* tooW   = (const float*)d_in[9];
  const float* toob   = (const float*)d_in[10];
  const float* bwW0   = (const float*)d_in[11];
  const float* bwb0   = (const float*)d_in[12];
  const float* bwW1   = (const float*)d_in[13];
  const float* bwb1   = (const float*)d_in[14];
  const float* modW0  = (const float*)d_in[15];
  const float* modb0  = (const float*)d_in[16];
  const float* modW1  = (const float*)d_in[17];
  const float* modb1  = (const float*)d_in[18];
  const float* hvW0   = (const float*)d_in[19];
  const float* hvb0   = (const float*)d_in[20];
  const float* outW0  = (const float*)d_in[21];
  const float* outb0  = (const float*)d_in[22];
  const float* outW1  = (const float*)d_in[23];
  const float* outb1  = (const float*)d_in[24];

  char* ws = (char*)d_ws;
  float*          t_ws   = (float*)(ws + 0);                  //   64 KB
  unsigned short* qc_ws  = (unsigned short*)(ws + 65536);     //    4 MB
  unsigned short* h0_hf  = (unsigned short*)(ws + 4259840);   //    8 MB
  unsigned short* h1_hf  = (unsigned short*)(ws + 12648448);  //    8 MB
  unsigned short* o_hf   = (unsigned short*)(ws + 21037056);  //   16 MB
  unsigned short* kn_ws  = (unsigned short*)(ws + 37814272);  //  256 KB
  unsigned short* vt_ws  = (unsigned short*)(ws + 38076416);  //  256 KB
  unsigned short* tooWt  = (unsigned short*)(ws + 38338560);  //   64 KB
  unsigned short* modW0t = (unsigned short*)(ws + 38404096);  //  128 KB
  unsigned short* modW1t = (unsigned short*)(ws + 38535168);  //  128 KB
  unsigned short* hvW0t  = (unsigned short*)(ws + 38666240);  //  128 KB
  unsigned short* qWt    = (unsigned short*)(ws + 38797312);  //   32 KB
  unsigned short* bw0t   = (unsigned short*)(ws + 38830080);  //   32 KB
  unsigned short* bw1t   = (unsigned short*)(ws + 38862848);  //   32 KB
  unsigned short* toqWt  = (unsigned short*)(ws + 38895616);  //   64 KB

  wprep_kernel<<<dim3(8), 256, 0, stream>>>(
      tooW, modW0, modW1, hvW0, qW, bwW0, bwW1, toqW,
      tooWt, modW0t, modW1t, hvW0t, qWt, bw0t, bw1t, toqWt);
  feat_kernel<<<dim3(kHW / 32), 256, 0, stream>>>(
      coords, Bq, Bl0, Bl1, qb, bwb0, bwb1,
      qWt, bw0t, bw1t, toqWt,
      t_ws, qc_ws, h0_hf, h1_hf);
  kv_kernel<<<dim3(kM, kB), 256, 0, stream>>>(tokens, tokvW, kn_ws, vt_ws);
  attn_kernel<<<dim3(kHW / 32, kB), 256, 0, stream>>>(kn_ws, vt_ws, qc_ws, t_ws, o_hf);
  mlp_kernel<<<dim3(kHW / 16), 256, 0, stream>>>(
      o_hf, h0_hf, h1_hf, tooWt, toob, modW0t, modb0, modW1t, modb1,
      hvW0t, hvb0, outW0, outb0, outW1, outb1, (float*)d_out);
}